// Round 12
// baseline (601.398 us; speedup 1.0000x reference)
//
#include <hip/hip_runtime.h>
#include <hip/hip_bf16.h>

#define NN 50000
#define EE 500000
#define GG 8
#define NB 196   // (NN+255)/256

#define SCALE_A 65536.0f          // agg fixed-point scale (2^16)
#define INV_SCALE_A (1.0f/65536.0f)
#define SCALE_G 16777216.0f       // graph-sum fixed-point scale (2^24)
#define INV_SCALE_G (1.0f/16777216.0f)

using short8 = __attribute__((ext_vector_type(8))) short;   // 8 bf16 (4 VGPR)
using f32x16 = __attribute__((ext_vector_type(16))) float;  // 32x32 accumulator

__device__ __forceinline__ float4 ld4(const float* p){ return *reinterpret_cast<const float4*>(p); }

__device__ __forceinline__ short f2b(float f){
  union { __hip_bfloat16 b; short s; } u;
  u.b = __float2bfloat16(f);
  return u.s;
}

// ---------------- degree count ----------------
__global__ __launch_bounds__(256) void k_count(const int* __restrict__ dst, int* __restrict__ cnt){
  int e = blockIdx.x*256 + threadIdx.x;
  if (e < EE) atomicAdd(&cnt[dst[e]], 1);
}

// ---------------- hierarchical exclusive scan ----------------
__global__ __launch_bounds__(256) void k_scanA(const int* __restrict__ cnt, int* __restrict__ bsum){
  __shared__ int s[256];
  int t = threadIdx.x;
  int i = blockIdx.x*256 + t;
  s[t] = (i < NN) ? cnt[i] : 0;
  __syncthreads();
  for (int o=128;o>0;o>>=1){ if (t<o) s[t]+=s[t+o]; __syncthreads(); }
  if (t==0) bsum[blockIdx.x] = s[0];
}

__global__ __launch_bounds__(256) void k_scanB(const int* __restrict__ bsum, int* __restrict__ boff){
  __shared__ int s[256];
  int t = threadIdx.x;
  s[t] = (t < NB) ? bsum[t] : 0;
  __syncthreads();
  for (int o=1;o<256;o<<=1){
    int u = (t>=o) ? s[t-o] : 0;
    __syncthreads();
    s[t] += u;
    __syncthreads();
  }
  if (t < NB) boff[t] = (t==0) ? 0 : s[t-1];
}

// scanC fused with per-node prep (inv, ncnt, bccnt)
__global__ __launch_bounds__(256) void k_scanC_prep(const int* __restrict__ cnt, const int* __restrict__ boff,
                                               int* __restrict__ offs,
                                               float* __restrict__ inv, const int* __restrict__ batch,
                                               const float* __restrict__ xm,
                                               float* __restrict__ ncnt, float* __restrict__ bccnt){
  __shared__ int s[256];
  __shared__ float lc[GG], lb[GG];
  int t = threadIdx.x;
  int i = blockIdx.x*256 + t;
  if (t < GG){ lc[t]=0.f; lb[t]=0.f; }
  int v = (i < NN) ? cnt[i] : 0;
  s[t] = v;
  __syncthreads();
  for (int o=1;o<256;o<<=1){
    int u = (t>=o) ? s[t-o] : 0;
    __syncthreads();
    s[t] += u;
    __syncthreads();
  }
  if (i < NN){
    offs[i] = boff[blockIdx.x] + s[t] - v;
    inv[i] = 1.0f / fmaxf((float)v, 1.0f);
    int g = batch[i];
    atomicAdd(&lc[g], 1.0f);
    atomicAdd(&lb[g], xm[i*3+2]);
  }
  __syncthreads();
  if (t < GG){ atomicAdd(&ncnt[t], lc[t]); atomicAdd(&bccnt[t], lb[t]); }
}

// ---------------- standalone prep (fallback path only) ----------------
__global__ __launch_bounds__(256) void k_prep(const int* __restrict__ cnt, float* __restrict__ inv,
                       const int* __restrict__ batch, const float* __restrict__ xm,
                       float* __restrict__ ncnt, float* __restrict__ bccnt){
  __shared__ float lc[GG], lb[GG];
  int t = threadIdx.x;
  if (t < GG){ lc[t]=0.f; lb[t]=0.f; }
  __syncthreads();
  int i = blockIdx.x*256 + t;
  if (i < NN){
    inv[i] = 1.0f / fmaxf((float)cnt[i], 1.0f);
    int g = batch[i];
    atomicAdd(&lc[g], 1.0f);
    atomicAdd(&lb[g], xm[i*3+2]);
  }
  __syncthreads();
  if (t < GG){ atomicAdd(&ncnt[t], lc[t]); atomicAdd(&bccnt[t], lb[t]); }
}

// ---------------- sort phase 1: scatter only perm (4B); offs becomes "end offset" ----------------
__global__ __launch_bounds__(256) void k_scat1(const int* __restrict__ dst, int* __restrict__ offs,
                                               int* __restrict__ perm){
  int e = blockIdx.x*256 + threadIdx.x;
  if (e >= EE) return;
  int d = dst[e];
  int pos = atomicAdd(&offs[d], 1);
  perm[pos] = e;
}

// ---------------- sort phase 2: gather via perm, coalesced writes ----------------
__global__ __launch_bounds__(256) void k_scat2(const int* __restrict__ perm,
                                               const int* __restrict__ src, const int* __restrict__ dst,
                                               const float* __restrict__ ea,
                                               int* __restrict__ srcs_s, int* __restrict__ dsts_s,
                                               short* __restrict__ ea16){
  int i = blockIdx.x*256 + threadIdx.x;
  if (i >= EE) return;
  int e = perm[i];
  srcs_s[i] = src[e];
  dsts_s[i] = dst[e];
  int lo = ((int)(unsigned short)f2b(ea[(size_t)e*3+0])) |
           (((int)(unsigned short)f2b(ea[(size_t)e*3+1])) << 16);
  int hi = ((int)(unsigned short)f2b(ea[(size_t)e*3+2]));
  int2 v; v.x = lo; v.y = hi;
  *(int2*)(ea16 + (size_t)i*4) = v;
}

// ---------------- weight pack: fp32 [K][64] -> bf16 MFMA B-fragment order ----------------
__device__ __forceinline__ void packone(const float* __restrict__ w, int Kreal, int idx, short* __restrict__ out){
  int k = idx >> 6, n = idx & 63;
  float v = (k < Kreal) ? w[k*64 + n] : 0.f;
  int ks = k >> 4, kl = k & 15;
  int lane = (n & 31) + 32*(kl >> 3);
  int e = kl & 7;
  out[(ks*2 + (n>>5))*512 + lane*8 + e] = f2b(v);
}

__global__ __launch_bounds__(256) void k_wpack(
    const float* __restrict__ mw1, const float* __restrict__ mw2,
    const float* __restrict__ uw1, const float* __restrict__ uw2,
    short* __restrict__ mw1p, short* __restrict__ mw2p,
    short* __restrict__ uw1p, short* __restrict__ uw2p){
  int gid = blockIdx.x*256 + threadIdx.x;
  int stride = gridDim.x*256;
  for (int i=gid; i<144*64; i+=stride) packone(mw1, 131, i, mw1p);
  for (int i=gid; i<64*64;  i+=stride) packone(mw2, 64,  i, mw2p);
  for (int i=gid; i<256*64; i+=stride) packone(uw1, 256, i, uw1p);
  for (int i=gid; i<64*64;  i+=stride) packone(uw2, 64,  i, uw2p);
}

// ---------------- encoder: LDS-staged coalesced output ----------------
__global__ __launch_bounds__(256) void k_enc(
    const float* __restrict__ x, const float* __restrict__ xm,
    const float* __restrict__ w1, const float* __restrict__ b1,
    const float* __restrict__ w2, const float* __restrict__ b2,
    float* __restrict__ h, short* __restrict__ h16){
  __shared__ float w1s[8*64];
  __shared__ float w2s[64*64];
  __shared__ float b1s[64], b2s[64];
  __shared__ float ols[4][64][17];
  int t = threadIdx.x;
  for (int i=t;i<8*64;i+=256) w1s[i]=w1[i];
  for (int i=t;i<64*64;i+=256) w2s[i]=w2[i];
  if (t<64){ b1s[t]=b1[t]; b2s[t]=b2[t]; }
  __syncthreads();
  const int w = t >> 6, lane = t & 63;
  const int base_w = blockIdx.x*256 + w*64;
  const int n = base_w + lane;
  const int nc = (n < NN) ? n : (NN-1);
  float in[8];
  #pragma unroll
  for (int k=0;k<5;k++) in[k] = x[nc*5+k];
  #pragma unroll
  for (int k=0;k<3;k++) in[5+k] = xm[nc*3+k];
  float hid[64];
  #pragma unroll
  for (int o=0;o<64;o++){
    float a = b1s[o];
    #pragma unroll
    for (int k=0;k<8;k++) a += in[k]*w1s[k*64+o];
    hid[o] = fmaxf(a, 0.f);
  }
  for (int c=0;c<4;c++){
    float a[16];
    #pragma unroll
    for (int j=0;j<16;j++) a[j] = b2s[c*16+j];
    for (int k=0;k<64;k++){
      float hv = hid[k];
      #pragma unroll
      for (int j=0;j<16;j++) a[j] += hv * w2s[k*64 + c*16 + j];
    }
    #pragma unroll
    for (int j=0;j<16;j++) ols[w][lane][j] = a[j];
    __syncthreads();
    #pragma unroll
    for (int p=0;p<4;p++){
      int nd = p*16 + (lane>>2);
      int jj = lane & 3;
      int ng = base_w + nd;
      if (ng < NN){
        float4 v = make_float4(ols[w][nd][jj*4+0], ols[w][nd][jj*4+1],
                               ols[w][nd][jj*4+2], ols[w][nd][jj*4+3]);
        *(float4*)(h + (size_t)ng*64 + c*16 + jj*4) = v;
      }
    }
    #pragma unroll
    for (int p=0;p<2;p++){
      int nd = p*32 + (lane>>1);
      int jj = (lane & 1)*8;
      int ng = base_w + nd;
      if (ng < NN){
        short8 s;
        #pragma unroll
        for (int q=0;q<8;q++) s[q] = f2b(ols[w][nd][jj+q]);
        *(short8*)(h16 + (size_t)ng*64 + c*16 + jj) = s;
      }
    }
    __syncthreads();
  }
}

// ---------------- per-graph reductions (initial, withBC) ----------------
__global__ __launch_bounds__(256) void k_gred(
    const float* __restrict__ h, const int* __restrict__ batch,
    const float* __restrict__ xm,
    unsigned long long* __restrict__ xg_sum, unsigned long long* __restrict__ xbc_sum, int withBC){
  __shared__ float ls[4][GG][64];
  __shared__ float lb[4][GG][64];
  int t = threadIdx.x;
  int d = t & 63, grp = t >> 6;
  for (int g=0; g<GG; g++){ ls[grp][g][d]=0.f; lb[grp][g][d]=0.f; }
  __syncthreads();
  for (int i = blockIdx.x*4 + grp; i < NN; i += gridDim.x*4){
    int g = batch[i];
    float v = h[(size_t)i*64 + d];
    ls[grp][g][d] += v;
    if (withBC) lb[grp][g][d] += v * xm[i*3+2];
  }
  __syncthreads();
  if (t < 64){
    for (int g=0; g<GG; g++){
      float s = ls[0][g][d]+ls[1][g][d]+ls[2][g][d]+ls[3][g][d];
      atomicAdd(&xg_sum[g*64+d], (unsigned long long)(long long)llrintf(s*SCALE_G));
    }
  } else if (withBC && t < 128){
    int dd = t & 63;
    for (int g=0; g<GG; g++){
      float s = lb[0][g][dd]+lb[1][g][dd]+lb[2][g][dd]+lb[3][g][dd];
      atomicAdd(&xbc_sum[g*64+dd], (unsigned long long)(long long)llrintf(s*SCALE_G));
    }
  }
}

// standalone gfin (fallback path only); zeroes xg_sum after reading
__global__ void k_gfin(unsigned long long* __restrict__ xg_sum, const unsigned long long* __restrict__ xbc_sum,
                       const float* __restrict__ ncnt, const float* __restrict__ bccnt,
                       short* __restrict__ xg16, short* __restrict__ xbc16, int withBC){
  int t = threadIdx.x; // 512
  int g = t >> 6;
  float sg = (float)(long long)xg_sum[t] * INV_SCALE_G;
  xg16[t] = f2b(sg / fmaxf(ncnt[g], 1.f));
  xg_sum[t] = 0;
  if (withBC){
    float sb = (float)(long long)xbc_sum[t] * INV_SCALE_G;
    xbc16[t] = f2b(sb / fmaxf(bccnt[g], 1.f));
  }
}

// ================= FUSED ROUND: pull-based msg + update, 1 wave / 32 dst nodes =================
// Block owns dst nodes [n0,n0+32) and their contiguous sorted edge range. Messages accumulate
// into LDS nodeagg (int fixed-point, block-exclusive -> plain adds, no global atomics).
// h16 double-buffered (h16in read, h16out written) to avoid cross-block races.
// Per-block local gfin from xgs_prev (previous dispatch) -> xgloc/xbcloc in LDS.
__global__ __launch_bounds__(64) void k_round(
    const short* __restrict__ h16in, short* __restrict__ h16out,
    float* __restrict__ h32,
    const int* __restrict__ srcs_s, const int* __restrict__ dsts_s,
    const short* __restrict__ ea16,
    const int* __restrict__ offsEnd, const int* __restrict__ cnt,
    const float* __restrict__ inv, const int* __restrict__ batch,
    const unsigned long long* __restrict__ xgs_prev,
    unsigned long long* __restrict__ xgs_next,
    const unsigned long long* __restrict__ xbc_sum,
    const float* __restrict__ ncnt, const float* __restrict__ bccnt,
    const short* __restrict__ mw1p, const float* __restrict__ mb1,
    const short* __restrict__ mw2p, const float* __restrict__ mb2,
    const short* __restrict__ uw1p, const float* __restrict__ ub1,
    const short* __restrict__ uw2p, const float* __restrict__ ub2,
    int withG){
  __shared__ int nodeagg[32*65];      // 8320 B (stride 65: bank-conflict-free column reads)
  __shared__ int buf[2304];           // 9216 B: hidT short[64][72] / mb int[32][65] / upd hidT
  __shared__ short xgloc[GG*64];      // 1024 B
  __shared__ short xbcloc[GG*64];     // 1024 B
  const int t = threadIdx.x;          // 0..63
  const int lane = t, r = lane & 31, khalf = lane >> 5;

  // local gfin (xgs_prev complete: written by previous dispatch)
  for (int i=t; i<GG*64; i+=64){
    int g = i >> 6;
    xgloc[i]  = f2b((float)(long long)xgs_prev[i] * INV_SCALE_G / fmaxf(ncnt[g], 1.f));
    xbcloc[i] = f2b((float)(long long)xbc_sum[i] * INV_SCALE_G / fmaxf(bccnt[g], 1.f));
  }
  for (int i=t; i<32*65; i+=64) nodeagg[i] = 0;

  const int n0 = blockIdx.x * 32;
  const int nLast = ((n0 + 32 <= NN) ? (n0 + 32) : NN) - 1;
  const int eStart = offsEnd[n0] - cnt[n0];
  const int eEnd   = offsEnd[nLast];

  const float b1v0 = mb1[r], b1v1 = mb1[32 + r];
  const float b2v0 = mb2[r], b2v1 = mb2[32 + r];
  const short8* w1f = (const short8*)mw1p;
  const short8* w2f = (const short8*)mw2p;
  short* hw = (short*)&buf[0];
  int* mb = &buf[0];

  for (int ebase = eStart; ebase < eEnd; ebase += 64){
    const int slot = ebase + lane;
    const int dl = (slot < eEnd) ? (dsts_s[slot] - n0) : -1;   // local dst 0..31, -1 invalid
    const int slotA = ebase + r, slotB = ebase + 32 + r;
    const bool vA = slotA < eEnd, vB = slotB < eEnd;
    const int sA = vA ? srcs_s[slotA] : 0;
    const int sB = vB ? srcs_s[slotB] : 0;
    int dAl = __shfl(dl, r);      const int dA = n0 + (dAl < 0 ? 0 : dAl);
    int dBl = __shfl(dl, 32 + r); const int dB = n0 + (dBl < 0 ? 0 : dBl);

    f32x16 acc00, acc01, acc10, acc11;
    #pragma unroll
    for (int j=0;j<16;j++){ acc00[j]=b1v0; acc01[j]=b1v1; acc10[j]=b1v0; acc11[j]=b1v1; }

    #pragma unroll
    for (int ks=0; ks<9; ks++){
      short8 a0, a1;
      if (ks < 8){
        long offA = (ks < 4) ? ((long)sA*64 + ks*16 + khalf*8) : ((long)dA*64 + (ks-4)*16 + khalf*8);
        long offB = (ks < 4) ? ((long)sB*64 + ks*16 + khalf*8) : ((long)dB*64 + (ks-4)*16 + khalf*8);
        a0 = *(const short8*)(h16in + offA);
        a1 = *(const short8*)(h16in + offB);
      } else {
        #pragma unroll
        for (int j=0;j<8;j++){ a0[j]=0; a1[j]=0; }
        if (khalf == 0){
          if (vA){
            int2 v = *(const int2*)(ea16 + (size_t)slotA*4);
            a0[0]=(short)v.x; a0[1]=(short)(v.x>>16); a0[2]=(short)v.y; a0[3]=(short)(v.y>>16);
          }
          if (vB){
            int2 v = *(const int2*)(ea16 + (size_t)slotB*4);
            a1[0]=(short)v.x; a1[1]=(short)(v.x>>16); a1[2]=(short)v.y; a1[3]=(short)(v.y>>16);
          }
        }
      }
      short8 bf0 = w1f[(ks*2+0)*64 + lane];
      short8 bf1 = w1f[(ks*2+1)*64 + lane];
      acc00 = __builtin_amdgcn_mfma_f32_32x32x16_bf16(a0, bf0, acc00, 0, 0, 0);
      acc01 = __builtin_amdgcn_mfma_f32_32x32x16_bf16(a0, bf1, acc01, 0, 0, 0);
      acc10 = __builtin_amdgcn_mfma_f32_32x32x16_bf16(a1, bf0, acc10, 0, 0, 0);
      acc11 = __builtin_amdgcn_mfma_f32_32x32x16_bf16(a1, bf1, acc11, 0, 0, 0);
    }

    #pragma unroll
    for (int reg=0; reg<16; reg++){
      int row = (reg&3) + 8*(reg>>2) + 4*khalf;
      hw[(row     )*72 + r     ] = f2b(fmaxf(acc00[reg], 0.f));
      hw[(row     )*72 + 32 + r] = f2b(fmaxf(acc01[reg], 0.f));
      hw[(row + 32)*72 + r     ] = f2b(fmaxf(acc10[reg], 0.f));
      hw[(row + 32)*72 + 32 + r] = f2b(fmaxf(acc11[reg], 0.f));
    }

    f32x16 c00, c01, c10, c11;
    #pragma unroll
    for (int j=0;j<16;j++){ c00[j]=b2v0; c01[j]=b2v1; c10[j]=b2v0; c11[j]=b2v1; }

    #pragma unroll
    for (int ks=0; ks<4; ks++){
      short8 p0 = *(const short8*)(hw + (r     )*72 + ks*16 + khalf*8);
      short8 p1 = *(const short8*)(hw + (32 + r)*72 + ks*16 + khalf*8);
      short8 bf0 = w2f[(ks*2+0)*64 + lane];
      short8 bf1 = w2f[(ks*2+1)*64 + lane];
      c00 = __builtin_amdgcn_mfma_f32_32x32x16_bf16(p0, bf0, c00, 0, 0, 0);
      c01 = __builtin_amdgcn_mfma_f32_32x32x16_bf16(p0, bf1, c01, 0, 0, 0);
      c10 = __builtin_amdgcn_mfma_f32_32x32x16_bf16(p1, bf0, c10, 0, 0, 0);
      c11 = __builtin_amdgcn_mfma_f32_32x32x16_bf16(p1, bf1, c11, 0, 0, 0);
    }

    // PASS A (chunk slots 0..31)
    #pragma unroll
    for (int reg=0; reg<16; reg++){
      int row = (reg&3) + 8*(reg>>2) + 4*khalf;
      mb[row*65 + r     ] = __float2int_rn(c00[reg]*SCALE_A);
      mb[row*65 + 32 + r] = __float2int_rn(c01[reg]*SCALE_A);
    }
    {
      int run = 0;
      #pragma unroll
      for (int rr=0; rr<32; rr++){ run += mb[rr*65 + lane]; mb[rr*65 + lane] = run; }
      int cur = 0;
      while (cur < 32){
        int d = __shfl(dl, cur);
        unsigned long long diff = __ballot(dl != d);
        unsigned low = (unsigned)diff;
        unsigned rest = low & (0xFFFFFFFEu << cur);
        int end = rest ? (__ffs(rest) - 1) : 32;
        if (d >= 0){
          int s = mb[(end-1)*65 + lane] - (cur ? mb[(cur-1)*65 + lane] : 0);
          nodeagg[d*65 + lane] += s;
        }
        cur = end;
      }
    }

    // PASS B (chunk slots 32..63)
    #pragma unroll
    for (int reg=0; reg<16; reg++){
      int row = (reg&3) + 8*(reg>>2) + 4*khalf;
      mb[row*65 + r     ] = __float2int_rn(c10[reg]*SCALE_A);
      mb[row*65 + 32 + r] = __float2int_rn(c11[reg]*SCALE_A);
    }
    {
      int run = 0;
      #pragma unroll
      for (int rr=0; rr<32; rr++){ run += mb[rr*65 + lane]; mb[rr*65 + lane] = run; }
      int cur = 0;
      while (cur < 32){
        int d = __shfl(dl, 32 + cur);
        unsigned long long diff = __ballot(dl != d);
        unsigned hi = (unsigned)(diff >> 32);
        unsigned rest = hi & (0xFFFFFFFEu << cur);
        int end = rest ? (__ffs(rest) - 1) : 32;
        if (d >= 0){
          int s = mb[(end-1)*65 + lane] - (cur ? mb[(cur-1)*65 + lane] : 0);
          nodeagg[d*65 + lane] += s;
        }
        cur = end;
      }
    }
  }

  // ---------------- update phase (same wave) ----------------
  const int n = n0 + r;
  const int nc = (n < NN) ? n : (NN-1);
  const int g = batch[nc];
  const float sc = inv[nc] * INV_SCALE_A;

  float ub1v0 = ub1[r], ub1v1 = ub1[32 + r];
  f32x16 a0acc, a1acc;
  #pragma unroll
  for (int j=0;j<16;j++){ a0acc[j]=ub1v0; a1acc[j]=ub1v1; }

  const short8* u1f = (const short8*)uw1p;
  #pragma unroll
  for (int ks=0; ks<16; ks++){
    short8 a;
    int so = (ks & 3)*16 + khalf*8;
    if (ks < 4){
      a = *(const short8*)(h16in + (long)nc*64 + so);
    } else if (ks < 8){
      #pragma unroll
      for (int j=0;j<8;j++) a[j] = f2b((float)nodeagg[r*65 + so + j] * sc);
    } else if (ks < 12){
      a = *(const short8*)(xgloc + g*64 + so);
    } else {
      a = *(const short8*)(xbcloc + g*64 + so);
    }
    short8 bf0 = u1f[(ks*2+0)*64 + lane];
    short8 bf1 = u1f[(ks*2+1)*64 + lane];
    a0acc = __builtin_amdgcn_mfma_f32_32x32x16_bf16(a, bf0, a0acc, 0, 0, 0);
    a1acc = __builtin_amdgcn_mfma_f32_32x32x16_bf16(a, bf1, a1acc, 0, 0, 0);
  }

  // hidT into buf (free after chunk loop)
  #pragma unroll
  for (int reg=0; reg<16; reg++){
    int row = (reg&3) + 8*(reg>>2) + 4*khalf;
    hw[row*72 + r     ] = f2b(fmaxf(a0acc[reg], 0.f));
    hw[row*72 + 32 + r] = f2b(fmaxf(a1acc[reg], 0.f));
  }

  float ub2v0 = ub2[r], ub2v1 = ub2[32 + r];
  f32x16 c0, c1;
  #pragma unroll
  for (int j=0;j<16;j++){ c0[j]=ub2v0; c1[j]=ub2v1; }

  const short8* u2f = (const short8*)uw2p;
  #pragma unroll
  for (int ks=0; ks<4; ks++){
    short8 a = *(const short8*)(hw + r*72 + ks*16 + khalf*8);
    short8 bf0 = u2f[(ks*2+0)*64 + lane];
    short8 bf1 = u2f[(ks*2+1)*64 + lane];
    c0 = __builtin_amdgcn_mfma_f32_32x32x16_bf16(a, bf0, c0, 0, 0, 0);
    c1 = __builtin_amdgcn_mfma_f32_32x32x16_bf16(a, bf1, c1, 0, 0, 0);
  }

  // epilogue: residual + h16out + fused graph sums (gs aliases nodeagg, done with it)
  unsigned long long* gs = (unsigned long long*)&nodeagg[0];   // 4096 B <= 8320 B
  const bool doG = (withG != 0);
  if (doG){ for (int i=t; i<GG*64; i+=64) gs[i] = 0; }
  const int g0 = __shfl(g, 0), g31 = __shfl(g, 31);
  const bool uni = (g0 == g31);
  long long s0 = 0, s1 = 0;
  #pragma unroll
  for (int reg=0; reg<16; reg++){
    int row = (reg&3) + 8*(reg>>2) + 4*khalf;
    int gg = __shfl(g, row);
    int nn = n0 + row;
    if (nn < NN){
      size_t i0 = (size_t)nn*64 + r;
      float v0 = h32[i0] + c0[reg];
      float v1 = h32[i0+32] + c1[reg];
      h32[i0] = v0;    h16out[i0] = f2b(v0);
      h32[i0+32] = v1; h16out[i0+32] = f2b(v1);
      if (doG){
        long long q0 = llrintf(v0*SCALE_G), q1 = llrintf(v1*SCALE_G);
        if (uni){ s0 += q0; s1 += q1; }
        else {
          atomicAdd(&gs[gg*64 + r     ], (unsigned long long)q0);
          atomicAdd(&gs[gg*64 + 32 + r], (unsigned long long)q1);
        }
      }
    }
  }
  if (doG && uni && (s0|s1)){
    atomicAdd(&gs[g0*64 + r     ], (unsigned long long)s0);
    atomicAdd(&gs[g0*64 + 32 + r], (unsigned long long)s1);
  }
  if (doG){
    for (int i=t; i<GG*64; i+=64){
      unsigned long long v = gs[i];
      if (v) atomicAdd(&xgs_next[i], v);
    }
  }
}

// ---------------- fallback: per-edge atomic scatter ----------------
__global__ __launch_bounds__(256) void k_msg_atomic(
    const short* __restrict__ h16, const int* __restrict__ src, const int* __restrict__ dst,
    const float* __restrict__ ea,
    const short* __restrict__ w1p, const float* __restrict__ b1,
    const short* __restrict__ w2p, const float* __restrict__ b2,
    int* __restrict__ agg){
  __shared__ short hidT[4][64*72];
  const int t = threadIdx.x;
  const int w = t >> 6, lane = t & 63;
  const int r = lane & 31, khalf = lane >> 5;
  const int base = blockIdx.x*256 + w*64;
  const int eA = base + r, eB = base + 32 + r;
  const bool vA = eA < EE, vB = eB < EE;
  const int sA = vA ? src[eA] : 0, dA_ = vA ? dst[eA] : 0;
  const int sB = vB ? src[eB] : 0, dB_ = vB ? dst[eB] : 0;

  float b1v0 = b1[r], b1v1 = b1[32 + r];
  f32x16 acc00, acc01, acc10, acc11;
  #pragma unroll
  for (int j=0;j<16;j++){ acc00[j]=b1v0; acc01[j]=b1v1; acc10[j]=b1v0; acc11[j]=b1v1; }

  const short8* w1f = (const short8*)w1p;
  #pragma unroll
  for (int ks=0; ks<9; ks++){
    short8 a0, a1;
    if (ks < 8){
      long offA, offB;
      if (ks < 4){
        offA = (long)sA*64 + ks*16 + khalf*8;
        offB = (long)sB*64 + ks*16 + khalf*8;
      } else {
        offA = (long)dA_*64 + (ks-4)*16 + khalf*8;
        offB = (long)dB_*64 + (ks-4)*16 + khalf*8;
      }
      a0 = *(const short8*)(h16 + offA);
      a1 = *(const short8*)(h16 + offB);
    } else {
      #pragma unroll
      for (int j=0;j<8;j++){ a0[j]=0; a1[j]=0; }
      if (khalf == 0){
        if (vA){ a0[0]=f2b(ea[3*eA]); a0[1]=f2b(ea[3*eA+1]); a0[2]=f2b(ea[3*eA+2]); }
        if (vB){ a1[0]=f2b(ea[3*eB]); a1[1]=f2b(ea[3*eB+1]); a1[2]=f2b(ea[3*eB+2]); }
      }
    }
    short8 bf0 = w1f[(ks*2+0)*64 + lane];
    short8 bf1 = w1f[(ks*2+1)*64 + lane];
    acc00 = __builtin_amdgcn_mfma_f32_32x32x16_bf16(a0, bf0, acc00, 0, 0, 0);
    acc01 = __builtin_amdgcn_mfma_f32_32x32x16_bf16(a0, bf1, acc01, 0, 0, 0);
    acc10 = __builtin_amdgcn_mfma_f32_32x32x16_bf16(a1, bf0, acc10, 0, 0, 0);
    acc11 = __builtin_amdgcn_mfma_f32_32x32x16_bf16(a1, bf1, acc11, 0, 0, 0);
  }

  short* hw = &hidT[w][0];
  #pragma unroll
  for (int reg=0; reg<16; reg++){
    int row = (reg&3) + 8*(reg>>2) + 4*khalf;
    hw[(row     )*72 + r     ] = f2b(fmaxf(acc00[reg], 0.f));
    hw[(row     )*72 + 32 + r] = f2b(fmaxf(acc01[reg], 0.f));
    hw[(row + 32)*72 + r     ] = f2b(fmaxf(acc10[reg], 0.f));
    hw[(row + 32)*72 + 32 + r] = f2b(fmaxf(acc11[reg], 0.f));
  }

  float b2v0 = b2[r], b2v1 = b2[32 + r];
  f32x16 c00, c01, c10, c11;
  #pragma unroll
  for (int j=0;j<16;j++){ c00[j]=b2v0; c01[j]=b2v1; c10[j]=b2v0; c11[j]=b2v1; }

  const short8* w2f = (const short8*)w2p;
  #pragma unroll
  for (int ks=0; ks<4; ks++){
    short8 a0 = *(const short8*)(hw + (r     )*72 + ks*16 + khalf*8);
    short8 a1 = *(const short8*)(hw + (32 + r)*72 + ks*16 + khalf*8);
    short8 bf0 = w2f[(ks*2+0)*64 + lane];
    short8 bf1 = w2f[(ks*2+1)*64 + lane];
    c00 = __builtin_amdgcn_mfma_f32_32x32x16_bf16(a0, bf0, c00, 0, 0, 0);
    c01 = __builtin_amdgcn_mfma_f32_32x32x16_bf16(a0, bf1, c01, 0, 0, 0);
    c10 = __builtin_amdgcn_mfma_f32_32x32x16_bf16(a1, bf0, c10, 0, 0, 0);
    c11 = __builtin_amdgcn_mfma_f32_32x32x16_bf16(a1, bf1, c11, 0, 0, 0);
  }

  #pragma unroll
  for (int reg=0; reg<16; reg++){
    int row = (reg&3) + 8*(reg>>2) + 4*khalf;
    int e0r = base + row;
    int e1r = base + 32 + row;
    int d0 = __shfl(dA_, row);
    int d1 = __shfl(dB_, row);
    if (e0r < EE){
      atomicAdd(&agg[(size_t)d0*64 + r     ], __float2int_rn(c00[reg]*SCALE_A));
      atomicAdd(&agg[(size_t)d0*64 + 32 + r], __float2int_rn(c01[reg]*SCALE_A));
    }
    if (e1r < EE){
      atomicAdd(&agg[(size_t)d1*64 + r     ], __float2int_rn(c10[reg]*SCALE_A));
      atomicAdd(&agg[(size_t)d1*64 + 32 + r], __float2int_rn(c11[reg]*SCALE_A));
    }
  }
}

// ---------------- fallback node update (unchanged from r11) ----------------
__global__ __launch_bounds__(64) void k_upd(
    float* __restrict__ h32, short* __restrict__ h16,
    int* __restrict__ agg, const float* __restrict__ inv,
    const int* __restrict__ batch,
    const short* __restrict__ xg16, const short* __restrict__ xbc16,
    const short* __restrict__ w1p, const float* __restrict__ b1,
    const short* __restrict__ w2p, const float* __restrict__ b2,
    unsigned long long* __restrict__ xg_sum, int withG){
  __shared__ short hidT[32*72];
  __shared__ unsigned long long gs[GG*64];
  const int t = threadIdx.x;
  for (int i=t; i<GG*64; i+=64) gs[i]=0;
  __syncthreads();

  const int lane = t;
  const int r = lane & 31, khalf = lane >> 5;
  const int n0 = blockIdx.x*32;
  const int n = n0 + r;
  const int nc = (n < NN) ? n : (NN-1);
  const int g = batch[nc];
  const float sc = inv[nc] * INV_SCALE_A;

  float b1v0 = b1[r], b1v1 = b1[32 + r];
  f32x16 a0acc, a1acc;
  #pragma unroll
  for (int j=0;j<16;j++){ a0acc[j]=b1v0; a1acc[j]=b1v1; }

  const short8* w1f = (const short8*)w1p;
  #pragma unroll
  for (int ks=0; ks<16; ks++){
    short8 a;
    int so = (ks & 3)*16 + khalf*8;
    if (ks < 4){
      a = *(const short8*)(h16 + (long)nc*64 + so);
    } else if (ks < 8){
      int4 i0 = *(const int4*)(agg + (long)nc*64 + so);
      int4 i1 = *(const int4*)(agg + (long)nc*64 + so + 4);
      if (n < NN){
        *(int4*)(agg + (long)nc*64 + so)     = make_int4(0,0,0,0);
        *(int4*)(agg + (long)nc*64 + so + 4) = make_int4(0,0,0,0);
      }
      a[0]=f2b((float)i0.x*sc); a[1]=f2b((float)i0.y*sc); a[2]=f2b((float)i0.z*sc); a[3]=f2b((float)i0.w*sc);
      a[4]=f2b((float)i1.x*sc); a[5]=f2b((float)i1.y*sc); a[6]=f2b((float)i1.z*sc); a[7]=f2b((float)i1.w*sc);
    } else if (ks < 12){
      a = *(const short8*)(xg16 + g*64 + so);
    } else {
      a = *(const short8*)(xbc16 + g*64 + so);
    }
    short8 bf0 = w1f[(ks*2+0)*64 + lane];
    short8 bf1 = w1f[(ks*2+1)*64 + lane];
    a0acc = __builtin_amdgcn_mfma_f32_32x32x16_bf16(a, bf0, a0acc, 0, 0, 0);
    a1acc = __builtin_amdgcn_mfma_f32_32x32x16_bf16(a, bf1, a1acc, 0, 0, 0);
  }

  short* hw = hidT;
  #pragma unroll
  for (int reg=0; reg<16; reg++){
    int row = (reg&3) + 8*(reg>>2) + 4*khalf;
    hw[row*72 + r     ] = f2b(fmaxf(a0acc[reg], 0.f));
    hw[row*72 + 32 + r] = f2b(fmaxf(a1acc[reg], 0.f));
  }

  float b2v0 = b2[r], b2v1 = b2[32 + r];
  f32x16 c0, c1;
  #pragma unroll
  for (int j=0;j<16;j++){ c0[j]=b2v0; c1[j]=b2v1; }

  const short8* w2f = (const short8*)w2p;
  #pragma unroll
  for (int ks=0; ks<4; ks++){
    short8 a = *(const short8*)(hw + r*72 + ks*16 + khalf*8);
    short8 bf0 = w2f[(ks*2+0)*64 + lane];
    short8 bf1 = w2f[(ks*2+1)*64 + lane];
    c0 = __builtin_amdgcn_mfma_f32_32x32x16_bf16(a, bf0, c0, 0, 0, 0);
    c1 = __builtin_amdgcn_mfma_f32_32x32x16_bf16(a, bf1, c1, 0, 0, 0);
  }

  const bool doG = (withG != 0);
  const int g0 = __shfl(g, 0), g31 = __shfl(g, 31);
  const bool uni = (g0 == g31);
  long long s0 = 0, s1 = 0;
  #pragma unroll
  for (int reg=0; reg<16; reg++){
    int row = (reg&3) + 8*(reg>>2) + 4*khalf;
    int gg = __shfl(g, row);
    int nn = n0 + row;
    if (nn < NN){
      size_t i0 = (size_t)nn*64 + r;
      float v0 = h32[i0] + c0[reg];
      float v1 = h32[i0+32] + c1[reg];
      h32[i0] = v0;    h16[i0] = f2b(v0);
      h32[i0+32] = v1; h16[i0+32] = f2b(v1);
      if (doG){
        long long q0 = llrintf(v0*SCALE_G), q1 = llrintf(v1*SCALE_G);
        if (uni){ s0 += q0; s1 += q1; }
        else {
          atomicAdd(&gs[gg*64 + r     ], (unsigned long long)q0);
          atomicAdd(&gs[gg*64 + 32 + r], (unsigned long long)q1);
        }
      }
    }
  }
  if (doG && uni && (s0|s1)){
    atomicAdd(&gs[g0*64 + r     ], (unsigned long long)s0);
    atomicAdd(&gs[g0*64 + 32 + r], (unsigned long long)s1);
  }
  __syncthreads();
  if (doG){
    for (int i=t; i<GG*64; i+=64){
      unsigned long long v = gs[i];
      if (v) atomicAdd(&xg_sum[i], v);
    }
  }
}

// ---------------- decoder ----------------
__global__ __launch_bounds__(256) void k_dec(
    const float* __restrict__ h,
    const float* __restrict__ w1, const float* __restrict__ b1,
    const float* __restrict__ w2, const float* __restrict__ b2,
    float* __restrict__ out){
  __shared__ float w1s[64*64];
  __shared__ float w2s[64*4];
  __shared__ float b1s[64], b2s[4];
  int t=threadIdx.x;
  for (int i=t;i<64*64;i+=256) w1s[i]=w1[i];
  for (int i=t;i<256;i+=256) w2s[i]=w2[i];
  if (t<64) b1s[t]=b1[t];
  if (t<4) b2s[t]=b2[t];
  __syncthreads();
  int n = blockIdx.x*256+t;
  if (n>=NN) return;
  float xr[64];
  #pragma unroll
  for (int k=0;k<16;k++){
    float4 v = ld4(h + (size_t)n*64 + k*4);
    xr[k*4+0]=v.x; xr[k*4+1]=v.y; xr[k*4+2]=v.z; xr[k*4+3]=v.w;
  }
  float a0=b2s[0],a1=b2s[1],a2=b2s[2],a3=b2s[3];
  for (int o=0;o<64;o++){
    float a=b1s[o];
    #pragma unroll
    for (int k=0;k<64;k++) a += xr[k]*w1s[k*64+o];
    a = fmaxf(a,0.f);
    a0 += a*w2s[o*4+0]; a1 += a*w2s[o*4+1]; a2 += a*w2s[o*4+2]; a3 += a*w2s[o*4+3];
  }
  out[(size_t)n*4+0]=a0; out[(size_t)n*4+1]=a1; out[(size_t)n*4+2]=a2; out[(size_t)n*4+3]=a3;
}

extern "C" void kernel_launch(void* const* d_in, const int* in_sizes, int n_in,
                              void* d_out, int out_size, void* d_ws, size_t ws_size,
                              hipStream_t stream){
  const float* x   = (const float*)d_in[0];
  const float* xm  = (const float*)d_in[1];
  const int*   ei  = (const int*)d_in[2];
  const float* ea  = (const float*)d_in[3];
  const int* batch = (const int*)d_in[5];
  const float* enc_w1=(const float*)d_in[6],  *enc_b1=(const float*)d_in[7];
  const float* enc_w2=(const float*)d_in[8],  *enc_b2=(const float*)d_in[9];
  const float* msg_w1=(const float*)d_in[10], *msg_b1=(const float*)d_in[11];
  const float* msg_w2=(const float*)d_in[12], *msg_b2=(const float*)d_in[13];
  const float* upd_w1=(const float*)d_in[14], *upd_b1=(const float*)d_in[15];
  const float* upd_w2=(const float*)d_in[16], *upd_b2=(const float*)d_in[17];
  const float* dec_w1=(const float*)d_in[18], *dec_b1=(const float*)d_in[19];
  const float* dec_w2=(const float*)d_in[20], *dec_b2=(const float*)d_in[21];
  const int* srcp = ei;
  const int* dstp = ei + EE;

  char* ws = (char*)d_ws;
  float* h32     = (float*)(ws + 0);             // 12,800,000
  int*   agg     = (int*)  (ws + 12800000);      // 12,800,000 (fallback); useSort: h16 buffer B
  int*   cnt     = (int*)  (ws + 25600000);      //    200,000
  unsigned long long* xgs = (unsigned long long*)(ws + 25800000);  // 4 × 4096 = 16,384
  unsigned long long* xbc_sum = (unsigned long long*)(ws + 25816384);  // 4096
  float* ncnt    = (float*)(ws + 25820480);      //        32
  float* bccnt   = (float*)(ws + 25820512);      //        32
  short* h16a    = (short*)(ws + 25820544);      //  6,400,000
  float* inv     = (float*)(ws + 32220544);      //    200,000
  short* xg16    = (short*)(ws + 32420544);      //      1024 (fallback)
  short* xbc16   = (short*)(ws + 32421568);      //      1024 (fallback)
  short* mw1p    = (short*)(ws + 32422592);      //     18432
  short* mw2p    = (short*)(ws + 32441024);      //      8192
  short* uw1p    = (short*)(ws + 32449216);      //     32768
  short* uw2p    = (short*)(ws + 32481984);      //      8192
  int*   offs    = (int*)  (ws + 32490176);      //    200,000 (post-scat1 = end offsets)
  int*   srcs_s  = (int*)  (ws + 32690176);      //  2,000,896
  int*   dsts_s  = (int*)  (ws + 34691072);      //  2,000,896
  short* ea16s   = (short*)(ws + 36691968);      //  4,001,792
  int*   bsum    = (int*)  (ws + 40693760);      //       800
  int*   boff    = (int*)  (ws + 40694560);      //       800
  int*   perm    = (int*)  (ws + 40695360);      //  2,000,896
  const size_t WS_NEED_SORT = 42696256;
  const int useSort = (ws_size >= WS_NEED_SORT) ? 1 : 0;
  short* h16b    = (short*)agg;                  // alias (useSort only)

  // zero: cnt + xgs[4] + xbc_sum + ncnt + bccnt (contiguous)
  hipMemsetAsync(ws + 25600000, 0, 220544, stream);
  if (!useSort) hipMemsetAsync(agg, 0, 12800000, stream);
  k_wpack<<<34, 256, 0, stream>>>(msg_w1, msg_w2, upd_w1, upd_w2, mw1p, mw2p, uw1p, uw2p);
  k_count<<<(EE+255)/256, 256, 0, stream>>>(dstp, cnt);
  if (useSort){
    k_scanA<<<NB, 256, 0, stream>>>(cnt, bsum);
    k_scanB<<<1, 256, 0, stream>>>(bsum, boff);
    k_scanC_prep<<<NB, 256, 0, stream>>>(cnt, boff, offs, inv, batch, xm, ncnt, bccnt);
    k_scat1<<<(EE+255)/256, 256, 0, stream>>>(dstp, offs, perm);
    k_scat2<<<(EE+255)/256, 256, 0, stream>>>(perm, srcp, dstp, ea, srcs_s, dsts_s, ea16s);
  } else {
    k_prep<<<(NN+255)/256, 256, 0, stream>>>(cnt, inv, batch, xm, ncnt, bccnt);
  }
  k_enc<<<(NN+255)/256, 256, 0, stream>>>(x, xm, enc_w1, enc_b1, enc_w2, enc_b2, h32, h16a);
  k_gred<<<512, 256, 0, stream>>>(h32, batch, xm, &xgs[0], xbc_sum, 1);

  if (useSort){
    for (int rp=0; rp<4; rp++){
      const short* hin  = (rp & 1) ? h16b : h16a;
      short*       hout = (rp & 1) ? h16a : h16b;
      int withG = (rp < 3) ? 1 : 0;
      k_round<<<(NN+31)/32, 64, 0, stream>>>(
          hin, hout, h32, srcs_s, dsts_s, ea16s, offs, cnt, inv, batch,
          &xgs[(size_t)rp*512], &xgs[(size_t)(rp+1 < 4 ? rp+1 : 3)*512], xbc_sum, ncnt, bccnt,
          mw1p, msg_b1, mw2p, msg_b2, uw1p, upd_b1, uw2p, upd_b2, withG);
    }
  } else {
    k_gfin<<<1, 512, 0, stream>>>(&xgs[0], xbc_sum, ncnt, bccnt, xg16, xbc16, 1);
    for (int rp=0; rp<4; rp++){
      k_msg_atomic<<<(EE+255)/256, 256, 0, stream>>>(h16a, srcp, dstp, ea, mw1p, msg_b1, mw2p, msg_b2, agg);
      int withG = (rp < 3) ? 1 : 0;
      k_upd<<<(NN+31)/32, 64, 0, stream>>>(h32, h16a, agg, inv, batch, xg16, xbc16, uw1p, upd_b1, uw2p, upd_b2, &xgs[0], withG);
      if (withG) k_gfin<<<1, 512, 0, stream>>>(&xgs[0], xbc_sum, ncnt, bccnt, xg16, xbc16, 0);
    }
  }
  k_dec<<<(NN+255)/256, 256, 0, stream>>>(h32, dec_w1, dec_b1, dec_w2, dec_b2, (float*)d_out);
}

// Round 13
// 406.583 us; speedup vs baseline: 1.4792x; 1.4792x over previous
//
#include <hip/hip_runtime.h>
#include <hip/hip_bf16.h>

#define NN 50000
#define EE 500000
#define GG 8
#define NB 196   // (NN+255)/256

#define SCALE_A 65536.0f          // agg fixed-point scale (2^16)
#define INV_SCALE_A (1.0f/65536.0f)
#define SCALE_G 16777216.0f       // graph-sum fixed-point scale (2^24)
#define INV_SCALE_G (1.0f/16777216.0f)

using short8 = __attribute__((ext_vector_type(8))) short;   // 8 bf16 (4 VGPR)
using f32x16 = __attribute__((ext_vector_type(16))) float;  // 32x32 accumulator

__device__ __forceinline__ float4 ld4(const float* p){ return *reinterpret_cast<const float4*>(p); }

__device__ __forceinline__ short f2b(float f){
  union { __hip_bfloat16 b; short s; } u;
  u.b = __float2bfloat16(f);
  return u.s;
}

// ---------------- degree count ----------------
__global__ __launch_bounds__(256) void k_count(const int* __restrict__ dst, int* __restrict__ cnt){
  int e = blockIdx.x*256 + threadIdx.x;
  if (e < EE) atomicAdd(&cnt[dst[e]], 1);
}

// ---------------- hierarchical exclusive scan ----------------
__global__ __launch_bounds__(256) void k_scanA(const int* __restrict__ cnt, int* __restrict__ bsum){
  __shared__ int s[256];
  int t = threadIdx.x;
  int i = blockIdx.x*256 + t;
  s[t] = (i < NN) ? cnt[i] : 0;
  __syncthreads();
  for (int o=128;o>0;o>>=1){ if (t<o) s[t]+=s[t+o]; __syncthreads(); }
  if (t==0) bsum[blockIdx.x] = s[0];
}

__global__ __launch_bounds__(256) void k_scanB(const int* __restrict__ bsum, int* __restrict__ boff){
  __shared__ int s[256];
  int t = threadIdx.x;
  s[t] = (t < NB) ? bsum[t] : 0;
  __syncthreads();
  for (int o=1;o<256;o<<=1){
    int u = (t>=o) ? s[t-o] : 0;
    __syncthreads();
    s[t] += u;
    __syncthreads();
  }
  if (t < NB) boff[t] = (t==0) ? 0 : s[t-1];
}

// scanC fused with per-node prep (inv, ncnt, bccnt)
__global__ __launch_bounds__(256) void k_scanC_prep(const int* __restrict__ cnt, const int* __restrict__ boff,
                                               int* __restrict__ offs,
                                               float* __restrict__ inv, const int* __restrict__ batch,
                                               const float* __restrict__ xm,
                                               float* __restrict__ ncnt, float* __restrict__ bccnt){
  __shared__ int s[256];
  __shared__ float lc[GG], lb[GG];
  int t = threadIdx.x;
  int i = blockIdx.x*256 + t;
  if (t < GG){ lc[t]=0.f; lb[t]=0.f; }
  int v = (i < NN) ? cnt[i] : 0;
  s[t] = v;
  __syncthreads();
  for (int o=1;o<256;o<<=1){
    int u = (t>=o) ? s[t-o] : 0;
    __syncthreads();
    s[t] += u;
    __syncthreads();
  }
  if (i < NN){
    offs[i] = boff[blockIdx.x] + s[t] - v;
    inv[i] = 1.0f / fmaxf((float)v, 1.0f);
    int g = batch[i];
    atomicAdd(&lc[g], 1.0f);
    atomicAdd(&lb[g], xm[i*3+2]);
  }
  __syncthreads();
  if (t < GG){ atomicAdd(&ncnt[t], lc[t]); atomicAdd(&bccnt[t], lb[t]); }
}

// ---------------- standalone prep (fallback path only) ----------------
__global__ __launch_bounds__(256) void k_prep(const int* __restrict__ cnt, float* __restrict__ inv,
                       const int* __restrict__ batch, const float* __restrict__ xm,
                       float* __restrict__ ncnt, float* __restrict__ bccnt){
  __shared__ float lc[GG], lb[GG];
  int t = threadIdx.x;
  if (t < GG){ lc[t]=0.f; lb[t]=0.f; }
  __syncthreads();
  int i = blockIdx.x*256 + t;
  if (i < NN){
    inv[i] = 1.0f / fmaxf((float)cnt[i], 1.0f);
    int g = batch[i];
    atomicAdd(&lc[g], 1.0f);
    atomicAdd(&lb[g], xm[i*3+2]);
  }
  __syncthreads();
  if (t < GG){ atomicAdd(&ncnt[t], lc[t]); atomicAdd(&bccnt[t], lb[t]); }
}

// ---------------- sort phase 1: scatter only perm (4B) ----------------
__global__ __launch_bounds__(256) void k_scat1(const int* __restrict__ dst, int* __restrict__ offs,
                                               int* __restrict__ perm){
  int e = blockIdx.x*256 + threadIdx.x;
  if (e >= EE) return;
  int d = dst[e];
  int pos = atomicAdd(&offs[d], 1);
  perm[pos] = e;
}

// ---------------- sort phase 2: gather via perm, coalesced writes ----------------
__global__ __launch_bounds__(256) void k_scat2(const int* __restrict__ perm,
                                               const int* __restrict__ src, const int* __restrict__ dst,
                                               const float* __restrict__ ea,
                                               int* __restrict__ srcs_s, int* __restrict__ dsts_s,
                                               short* __restrict__ ea16){
  int i = blockIdx.x*256 + threadIdx.x;
  if (i >= EE) return;
  int e = perm[i];
  srcs_s[i] = src[e];
  dsts_s[i] = dst[e];
  int lo = ((int)(unsigned short)f2b(ea[(size_t)e*3+0])) |
           (((int)(unsigned short)f2b(ea[(size_t)e*3+1])) << 16);
  int hi = ((int)(unsigned short)f2b(ea[(size_t)e*3+2]));
  int2 v; v.x = lo; v.y = hi;
  *(int2*)(ea16 + (size_t)i*4) = v;
}

// ---------------- weight pack: fp32 [K][64] -> bf16 MFMA B-fragment order ----------------
__device__ __forceinline__ void packone(const float* __restrict__ w, int Kreal, int idx, short* __restrict__ out){
  int k = idx >> 6, n = idx & 63;
  float v = (k < Kreal) ? w[k*64 + n] : 0.f;
  int ks = k >> 4, kl = k & 15;
  int lane = (n & 31) + 32*(kl >> 3);
  int e = kl & 7;
  out[(ks*2 + (n>>5))*512 + lane*8 + e] = f2b(v);
}

__global__ __launch_bounds__(256) void k_wpack(
    const float* __restrict__ mw1, const float* __restrict__ mw2,
    const float* __restrict__ uw1, const float* __restrict__ uw2,
    short* __restrict__ mw1p, short* __restrict__ mw2p,
    short* __restrict__ uw1p, short* __restrict__ uw2p){
  int gid = blockIdx.x*256 + threadIdx.x;
  int stride = gridDim.x*256;
  for (int i=gid; i<144*64; i+=stride) packone(mw1, 131, i, mw1p);
  for (int i=gid; i<64*64;  i+=stride) packone(mw2, 64,  i, mw2p);
  for (int i=gid; i<256*64; i+=stride) packone(uw1, 256, i, uw1p);
  for (int i=gid; i<64*64;  i+=stride) packone(uw2, 64,  i, uw2p);
}

// ---------------- encoder: LDS-staged coalesced output ----------------
__global__ __launch_bounds__(256) void k_enc(
    const float* __restrict__ x, const float* __restrict__ xm,
    const float* __restrict__ w1, const float* __restrict__ b1,
    const float* __restrict__ w2, const float* __restrict__ b2,
    float* __restrict__ h, short* __restrict__ h16){
  __shared__ float w1s[8*64];
  __shared__ float w2s[64*64];
  __shared__ float b1s[64], b2s[64];
  __shared__ float ols[4][64][17];
  int t = threadIdx.x;
  for (int i=t;i<8*64;i+=256) w1s[i]=w1[i];
  for (int i=t;i<64*64;i+=256) w2s[i]=w2[i];
  if (t<64){ b1s[t]=b1[t]; b2s[t]=b2[t]; }
  __syncthreads();
  const int w = t >> 6, lane = t & 63;
  const int base_w = blockIdx.x*256 + w*64;
  const int n = base_w + lane;
  const int nc = (n < NN) ? n : (NN-1);
  float in[8];
  #pragma unroll
  for (int k=0;k<5;k++) in[k] = x[nc*5+k];
  #pragma unroll
  for (int k=0;k<3;k++) in[5+k] = xm[nc*3+k];
  float hid[64];
  #pragma unroll
  for (int o=0;o<64;o++){
    float a = b1s[o];
    #pragma unroll
    for (int k=0;k<8;k++) a += in[k]*w1s[k*64+o];
    hid[o] = fmaxf(a, 0.f);
  }
  for (int c=0;c<4;c++){
    float a[16];
    #pragma unroll
    for (int j=0;j<16;j++) a[j] = b2s[c*16+j];
    for (int k=0;k<64;k++){
      float hv = hid[k];
      #pragma unroll
      for (int j=0;j<16;j++) a[j] += hv * w2s[k*64 + c*16 + j];
    }
    #pragma unroll
    for (int j=0;j<16;j++) ols[w][lane][j] = a[j];
    __syncthreads();
    #pragma unroll
    for (int p=0;p<4;p++){
      int nd = p*16 + (lane>>2);
      int jj = lane & 3;
      int ng = base_w + nd;
      if (ng < NN){
        float4 v = make_float4(ols[w][nd][jj*4+0], ols[w][nd][jj*4+1],
                               ols[w][nd][jj*4+2], ols[w][nd][jj*4+3]);
        *(float4*)(h + (size_t)ng*64 + c*16 + jj*4) = v;
      }
    }
    #pragma unroll
    for (int p=0;p<2;p++){
      int nd = p*32 + (lane>>1);
      int jj = (lane & 1)*8;
      int ng = base_w + nd;
      if (ng < NN){
        short8 s;
        #pragma unroll
        for (int q=0;q<8;q++) s[q] = f2b(ols[w][nd][jj+q]);
        *(short8*)(h16 + (size_t)ng*64 + c*16 + jj) = s;
      }
    }
    __syncthreads();
  }
}

// ---------------- per-graph reductions (initial, withBC) ----------------
__global__ __launch_bounds__(256) void k_gred(
    const float* __restrict__ h, const int* __restrict__ batch,
    const float* __restrict__ xm,
    unsigned long long* __restrict__ xg_sum, unsigned long long* __restrict__ xbc_sum, int withBC){
  __shared__ float ls[4][GG][64];
  __shared__ float lb[4][GG][64];
  int t = threadIdx.x;
  int d = t & 63, grp = t >> 6;
  for (int g=0; g<GG; g++){ ls[grp][g][d]=0.f; lb[grp][g][d]=0.f; }
  __syncthreads();
  for (int i = blockIdx.x*4 + grp; i < NN; i += gridDim.x*4){
    int g = batch[i];
    float v = h[(size_t)i*64 + d];
    ls[grp][g][d] += v;
    if (withBC) lb[grp][g][d] += v * xm[i*3+2];
  }
  __syncthreads();
  if (t < 64){
    for (int g=0; g<GG; g++){
      float s = ls[0][g][d]+ls[1][g][d]+ls[2][g][d]+ls[3][g][d];
      atomicAdd(&xg_sum[g*64+d], (unsigned long long)(long long)llrintf(s*SCALE_G));
    }
  } else if (withBC && t < 128){
    int dd = t & 63;
    for (int g=0; g<GG; g++){
      float s = lb[0][g][dd]+lb[1][g][dd]+lb[2][g][dd]+lb[3][g][dd];
      atomicAdd(&xbc_sum[g*64+dd], (unsigned long long)(long long)llrintf(s*SCALE_G));
    }
  }
}

// standalone gfin (fallback path only); zeroes xg_sum after reading
__global__ void k_gfin(unsigned long long* __restrict__ xg_sum, const unsigned long long* __restrict__ xbc_sum,
                       const float* __restrict__ ncnt, const float* __restrict__ bccnt,
                       short* __restrict__ xg16, short* __restrict__ xbc16, int withBC){
  int t = threadIdx.x; // 512
  int g = t >> 6;
  float sg = (float)(long long)xg_sum[t] * INV_SCALE_G;
  xg16[t] = f2b(sg / fmaxf(ncnt[g], 1.f));
  xg_sum[t] = 0;
  if (withBC){
    float sb = (float)(long long)xbc_sum[t] * INV_SCALE_G;
    xbc16[t] = f2b(sb / fmaxf(bccnt[g], 1.f));
  }
}

// ---------------- message MLP via MFMA bf16 (1-wave blocks, prefix-sum walk, setprio) ----------------
__global__ __launch_bounds__(64) void k_msg_s(
    const short* __restrict__ h16,
    const int* __restrict__ srcs_s, const int* __restrict__ dsts_s,
    const short* __restrict__ ea16,
    const short* __restrict__ w1p, const float* __restrict__ b1,
    const short* __restrict__ w2p, const float* __restrict__ b2,
    int* __restrict__ agg,
    unsigned long long* __restrict__ xg_sum, const unsigned long long* __restrict__ xbc_sum,
    const float* __restrict__ ncnt, const float* __restrict__ bccnt,
    short* __restrict__ xg16, short* __restrict__ xbc16, int withBC){
  __shared__ int buf[2304];   // 9216 B: hidT (short[64][72]) then msg (int[32][65])
  const int t = threadIdx.x;             // 0..63
  if (blockIdx.x == 0){
    for (int i=t; i<GG*64; i+=64){
      int g = i >> 6;
      float sg = (float)(long long)xg_sum[i] * INV_SCALE_G;
      xg16[i] = f2b(sg / fmaxf(ncnt[g], 1.f));
      xg_sum[i] = 0;
      if (withBC){
        float sb = (float)(long long)xbc_sum[i] * INV_SCALE_G;
        xbc16[i] = f2b(sb / fmaxf(bccnt[g], 1.f));
      }
    }
  }
  // bijective XCD-aware swizzle (m204)
  const int nwg = gridDim.x;
  const int q = nwg >> 3, rm = nwg & 7;
  const int xcd = blockIdx.x & 7, idx = blockIdx.x >> 3;
  const int wg = (xcd < rm ? xcd*(q+1) : rm*(q+1) + (xcd-rm)*q) + idx;
  const int base = wg * 64;

  const int lane = t;
  const int r = lane & 31, khalf = lane >> 5;
  const int slot = base + lane;
  const int dl = (slot < EE) ? dsts_s[slot] : -1;

  const int eA = base + r, eB = base + 32 + r;
  const bool vA = eA < EE, vB = eB < EE;
  const int sA = vA ? srcs_s[eA] : 0;
  const int sB = vB ? srcs_s[eB] : 0;
  int dA = __shfl(dl, r);        if (dA < 0) dA = 0;
  int dB = __shfl(dl, 32 + r);   if (dB < 0) dB = 0;

  float b1v0 = b1[r], b1v1 = b1[32 + r];
  f32x16 acc00, acc01, acc10, acc11;
  #pragma unroll
  for (int j=0;j<16;j++){ acc00[j]=b1v0; acc01[j]=b1v1; acc10[j]=b1v0; acc11[j]=b1v1; }

  const short8* w1f = (const short8*)w1p;
  __builtin_amdgcn_s_setprio(1);
  #pragma unroll
  for (int ks=0; ks<9; ks++){
    short8 a0, a1;
    if (ks < 8){
      long offA, offB;
      if (ks < 4){
        offA = (long)sA*64 + ks*16 + khalf*8;
        offB = (long)sB*64 + ks*16 + khalf*8;
      } else {
        offA = (long)dA*64 + (ks-4)*16 + khalf*8;
        offB = (long)dB*64 + (ks-4)*16 + khalf*8;
      }
      a0 = *(const short8*)(h16 + offA);
      a1 = *(const short8*)(h16 + offB);
    } else {
      #pragma unroll
      for (int j=0;j<8;j++){ a0[j]=0; a1[j]=0; }
      if (khalf == 0){
        if (vA){
          int2 v = *(const int2*)(ea16 + (size_t)eA*4);
          a0[0]=(short)v.x; a0[1]=(short)(v.x>>16); a0[2]=(short)v.y; a0[3]=(short)(v.y>>16);
        }
        if (vB){
          int2 v = *(const int2*)(ea16 + (size_t)eB*4);
          a1[0]=(short)v.x; a1[1]=(short)(v.x>>16); a1[2]=(short)v.y; a1[3]=(short)(v.y>>16);
        }
      }
    }
    short8 bf0 = w1f[(ks*2+0)*64 + lane];
    short8 bf1 = w1f[(ks*2+1)*64 + lane];
    acc00 = __builtin_amdgcn_mfma_f32_32x32x16_bf16(a0, bf0, acc00, 0, 0, 0);
    acc01 = __builtin_amdgcn_mfma_f32_32x32x16_bf16(a0, bf1, acc01, 0, 0, 0);
    acc10 = __builtin_amdgcn_mfma_f32_32x32x16_bf16(a1, bf0, acc10, 0, 0, 0);
    acc11 = __builtin_amdgcn_mfma_f32_32x32x16_bf16(a1, bf1, acc11, 0, 0, 0);
  }
  __builtin_amdgcn_s_setprio(0);

  short* hw = (short*)&buf[0];
  #pragma unroll
  for (int reg=0; reg<16; reg++){
    int row = (reg&3) + 8*(reg>>2) + 4*khalf;
    hw[(row     )*72 + r     ] = f2b(fmaxf(acc00[reg], 0.f));
    hw[(row     )*72 + 32 + r] = f2b(fmaxf(acc01[reg], 0.f));
    hw[(row + 32)*72 + r     ] = f2b(fmaxf(acc10[reg], 0.f));
    hw[(row + 32)*72 + 32 + r] = f2b(fmaxf(acc11[reg], 0.f));
  }

  float b2v0 = b2[r], b2v1 = b2[32 + r];
  f32x16 c00, c01, c10, c11;
  #pragma unroll
  for (int j=0;j<16;j++){ c00[j]=b2v0; c01[j]=b2v1; c10[j]=b2v0; c11[j]=b2v1; }

  const short8* w2f = (const short8*)w2p;
  __builtin_amdgcn_s_setprio(1);
  #pragma unroll
  for (int ks=0; ks<4; ks++){
    short8 p0 = *(const short8*)(hw + (r     )*72 + ks*16 + khalf*8);
    short8 p1 = *(const short8*)(hw + (32 + r)*72 + ks*16 + khalf*8);
    short8 bf0 = w2f[(ks*2+0)*64 + lane];
    short8 bf1 = w2f[(ks*2+1)*64 + lane];
    c00 = __builtin_amdgcn_mfma_f32_32x32x16_bf16(p0, bf0, c00, 0, 0, 0);
    c01 = __builtin_amdgcn_mfma_f32_32x32x16_bf16(p0, bf1, c01, 0, 0, 0);
    c10 = __builtin_amdgcn_mfma_f32_32x32x16_bf16(p1, bf0, c10, 0, 0, 0);
    c11 = __builtin_amdgcn_mfma_f32_32x32x16_bf16(p1, bf1, c11, 0, 0, 0);
  }
  __builtin_amdgcn_s_setprio(0);

  int* mb = &buf[0];

  // PASS A (slots base..base+31)
  #pragma unroll
  for (int reg=0; reg<16; reg++){
    int row = (reg&3) + 8*(reg>>2) + 4*khalf;
    mb[row*65 + r     ] = __float2int_rn(c00[reg]*SCALE_A);
    mb[row*65 + 32 + r] = __float2int_rn(c01[reg]*SCALE_A);
  }
  {
    int run = 0;
    #pragma unroll
    for (int rr=0; rr<32; rr++){ run += mb[rr*65 + lane]; mb[rr*65 + lane] = run; }
    int cur = 0;
    while (cur < 32){
      int d = __shfl(dl, cur);
      unsigned long long diff = __ballot(dl != d);
      unsigned low = (unsigned)diff;
      unsigned rest = low & (0xFFFFFFFEu << cur);
      int end = rest ? (__ffs(rest) - 1) : 32;
      if (d >= 0){
        int s = mb[(end-1)*65 + lane] - (cur ? mb[(cur-1)*65 + lane] : 0);
        atomicAdd(&agg[(size_t)d*64 + lane], s);
      }
      cur = end;
    }
  }

  // PASS B (slots base+32..base+63)
  #pragma unroll
  for (int reg=0; reg<16; reg++){
    int row = (reg&3) + 8*(reg>>2) + 4*khalf;
    mb[row*65 + r     ] = __float2int_rn(c10[reg]*SCALE_A);
    mb[row*65 + 32 + r] = __float2int_rn(c11[reg]*SCALE_A);
  }
  {
    int run = 0;
    #pragma unroll
    for (int rr=0; rr<32; rr++){ run += mb[rr*65 + lane]; mb[rr*65 + lane] = run; }
    int cur = 0;
    while (cur < 32){
      int d = __shfl(dl, 32 + cur);
      unsigned long long diff = __ballot(dl != d);
      unsigned hi = (unsigned)(diff >> 32);
      unsigned rest = hi & (0xFFFFFFFEu << cur);
      int end = rest ? (__ffs(rest) - 1) : 32;
      if (d >= 0){
        int s = mb[(end-1)*65 + lane] - (cur ? mb[(cur-1)*65 + lane] : 0);
        atomicAdd(&agg[(size_t)d*64 + lane], s);
      }
      cur = end;
    }
  }
}

// ---------------- fallback: per-edge atomic scatter ----------------
__global__ __launch_bounds__(256) void k_msg_atomic(
    const short* __restrict__ h16, const int* __restrict__ src, const int* __restrict__ dst,
    const float* __restrict__ ea,
    const short* __restrict__ w1p, const float* __restrict__ b1,
    const short* __restrict__ w2p, const float* __restrict__ b2,
    int* __restrict__ agg){
  __shared__ short hidT[4][64*72];
  const int t = threadIdx.x;
  const int w = t >> 6, lane = t & 63;
  const int r = lane & 31, khalf = lane >> 5;
  const int base = blockIdx.x*256 + w*64;
  const int eA = base + r, eB = base + 32 + r;
  const bool vA = eA < EE, vB = eB < EE;
  const int sA = vA ? src[eA] : 0, dA_ = vA ? dst[eA] : 0;
  const int sB = vB ? src[eB] : 0, dB_ = vB ? dst[eB] : 0;

  float b1v0 = b1[r], b1v1 = b1[32 + r];
  f32x16 acc00, acc01, acc10, acc11;
  #pragma unroll
  for (int j=0;j<16;j++){ acc00[j]=b1v0; acc01[j]=b1v1; acc10[j]=b1v0; acc11[j]=b1v1; }

  const short8* w1f = (const short8*)w1p;
  #pragma unroll
  for (int ks=0; ks<9; ks++){
    short8 a0, a1;
    if (ks < 8){
      long offA, offB;
      if (ks < 4){
        offA = (long)sA*64 + ks*16 + khalf*8;
        offB = (long)sB*64 + ks*16 + khalf*8;
      } else {
        offA = (long)dA_*64 + (ks-4)*16 + khalf*8;
        offB = (long)dB_*64 + (ks-4)*16 + khalf*8;
      }
      a0 = *(const short8*)(h16 + offA);
      a1 = *(const short8*)(h16 + offB);
    } else {
      #pragma unroll
      for (int j=0;j<8;j++){ a0[j]=0; a1[j]=0; }
      if (khalf == 0){
        if (vA){ a0[0]=f2b(ea[3*eA]); a0[1]=f2b(ea[3*eA+1]); a0[2]=f2b(ea[3*eA+2]); }
        if (vB){ a1[0]=f2b(ea[3*eB]); a1[1]=f2b(ea[3*eB+1]); a1[2]=f2b(ea[3*eB+2]); }
      }
    }
    short8 bf0 = w1f[(ks*2+0)*64 + lane];
    short8 bf1 = w1f[(ks*2+1)*64 + lane];
    acc00 = __builtin_amdgcn_mfma_f32_32x32x16_bf16(a0, bf0, acc00, 0, 0, 0);
    acc01 = __builtin_amdgcn_mfma_f32_32x32x16_bf16(a0, bf1, acc01, 0, 0, 0);
    acc10 = __builtin_amdgcn_mfma_f32_32x32x16_bf16(a1, bf0, acc10, 0, 0, 0);
    acc11 = __builtin_amdgcn_mfma_f32_32x32x16_bf16(a1, bf1, acc11, 0, 0, 0);
  }

  short* hw = &hidT[w][0];
  #pragma unroll
  for (int reg=0; reg<16; reg++){
    int row = (reg&3) + 8*(reg>>2) + 4*khalf;
    hw[(row     )*72 + r     ] = f2b(fmaxf(acc00[reg], 0.f));
    hw[(row     )*72 + 32 + r] = f2b(fmaxf(acc01[reg], 0.f));
    hw[(row + 32)*72 + r     ] = f2b(fmaxf(acc10[reg], 0.f));
    hw[(row + 32)*72 + 32 + r] = f2b(fmaxf(acc11[reg], 0.f));
  }

  float b2v0 = b2[r], b2v1 = b2[32 + r];
  f32x16 c00, c01, c10, c11;
  #pragma unroll
  for (int j=0;j<16;j++){ c00[j]=b2v0; c01[j]=b2v1; c10[j]=b2v0; c11[j]=b2v1; }

  const short8* w2f = (const short8*)w2p;
  #pragma unroll
  for (int ks=0; ks<4; ks++){
    short8 a0 = *(const short8*)(hw + (r     )*72 + ks*16 + khalf*8);
    short8 a1 = *(const short8*)(hw + (32 + r)*72 + ks*16 + khalf*8);
    short8 bf0 = w2f[(ks*2+0)*64 + lane];
    short8 bf1 = w2f[(ks*2+1)*64 + lane];
    c00 = __builtin_amdgcn_mfma_f32_32x32x16_bf16(a0, bf0, c00, 0, 0, 0);
    c01 = __builtin_amdgcn_mfma_f32_32x32x16_bf16(a0, bf1, c01, 0, 0, 0);
    c10 = __builtin_amdgcn_mfma_f32_32x32x16_bf16(a1, bf0, c10, 0, 0, 0);
    c11 = __builtin_amdgcn_mfma_f32_32x32x16_bf16(a1, bf1, c11, 0, 0, 0);
  }

  #pragma unroll
  for (int reg=0; reg<16; reg++){
    int row = (reg&3) + 8*(reg>>2) + 4*khalf;
    int e0r = base + row;
    int e1r = base + 32 + row;
    int d0 = __shfl(dA_, row);
    int d1 = __shfl(dB_, row);
    if (e0r < EE){
      atomicAdd(&agg[(size_t)d0*64 + r     ], __float2int_rn(c00[reg]*SCALE_A));
      atomicAdd(&agg[(size_t)d0*64 + 32 + r], __float2int_rn(c01[reg]*SCALE_A));
    }
    if (e1r < EE){
      atomicAdd(&agg[(size_t)d1*64 + r     ], __float2int_rn(c10[reg]*SCALE_A));
      atomicAdd(&agg[(size_t)d1*64 + 32 + r], __float2int_rn(c11[reg]*SCALE_A));
    }
  }
}

// ---------------- node update MLP (1-wave blocks), fused graph-reduction + agg re-zero ----------------
__global__ __launch_bounds__(64) void k_upd(
    float* __restrict__ h32, short* __restrict__ h16,
    int* __restrict__ agg, const float* __restrict__ inv,
    const int* __restrict__ batch,
    const short* __restrict__ xg16, const short* __restrict__ xbc16,
    const short* __restrict__ w1p, const float* __restrict__ b1,
    const short* __restrict__ w2p, const float* __restrict__ b2,
    unsigned long long* __restrict__ xg_sum, int withG){
  __shared__ short hidT[32*72];          // 4608 B
  __shared__ unsigned long long gs[GG*64]; // 4096 B
  const int t = threadIdx.x;             // 0..63
  for (int i=t; i<GG*64; i+=64) gs[i]=0;
  __syncthreads();

  const int lane = t;
  const int r = lane & 31, khalf = lane >> 5;
  const int n0 = blockIdx.x*32;
  const int n = n0 + r;
  const int nc = (n < NN) ? n : (NN-1);
  const int g = batch[nc];
  const float sc = inv[nc] * INV_SCALE_A;

  float b1v0 = b1[r], b1v1 = b1[32 + r];
  f32x16 a0acc, a1acc;
  #pragma unroll
  for (int j=0;j<16;j++){ a0acc[j]=b1v0; a1acc[j]=b1v1; }

  const short8* w1f = (const short8*)w1p;
  __builtin_amdgcn_s_setprio(1);
  #pragma unroll
  for (int ks=0; ks<16; ks++){
    short8 a;
    int so = (ks & 3)*16 + khalf*8;
    if (ks < 4){
      a = *(const short8*)(h16 + (long)nc*64 + so);
    } else if (ks < 8){
      int4 i0 = *(const int4*)(agg + (long)nc*64 + so);
      int4 i1 = *(const int4*)(agg + (long)nc*64 + so + 4);
      if (n < NN){
        *(int4*)(agg + (long)nc*64 + so)     = make_int4(0,0,0,0);
        *(int4*)(agg + (long)nc*64 + so + 4) = make_int4(0,0,0,0);
      }
      a[0]=f2b((float)i0.x*sc); a[1]=f2b((float)i0.y*sc); a[2]=f2b((float)i0.z*sc); a[3]=f2b((float)i0.w*sc);
      a[4]=f2b((float)i1.x*sc); a[5]=f2b((float)i1.y*sc); a[6]=f2b((float)i1.z*sc); a[7]=f2b((float)i1.w*sc);
    } else if (ks < 12){
      a = *(const short8*)(xg16 + g*64 + so);
    } else {
      a = *(const short8*)(xbc16 + g*64 + so);
    }
    short8 bf0 = w1f[(ks*2+0)*64 + lane];
    short8 bf1 = w1f[(ks*2+1)*64 + lane];
    a0acc = __builtin_amdgcn_mfma_f32_32x32x16_bf16(a, bf0, a0acc, 0, 0, 0);
    a1acc = __builtin_amdgcn_mfma_f32_32x32x16_bf16(a, bf1, a1acc, 0, 0, 0);
  }
  __builtin_amdgcn_s_setprio(0);

  short* hw = hidT;
  #pragma unroll
  for (int reg=0; reg<16; reg++){
    int row = (reg&3) + 8*(reg>>2) + 4*khalf;
    hw[row*72 + r     ] = f2b(fmaxf(a0acc[reg], 0.f));
    hw[row*72 + 32 + r] = f2b(fmaxf(a1acc[reg], 0.f));
  }

  float b2v0 = b2[r], b2v1 = b2[32 + r];
  f32x16 c0, c1;
  #pragma unroll
  for (int j=0;j<16;j++){ c0[j]=b2v0; c1[j]=b2v1; }

  const short8* w2f = (const short8*)w2p;
  __builtin_amdgcn_s_setprio(1);
  #pragma unroll
  for (int ks=0; ks<4; ks++){
    short8 a = *(const short8*)(hw + r*72 + ks*16 + khalf*8);
    short8 bf0 = w2f[(ks*2+0)*64 + lane];
    short8 bf1 = w2f[(ks*2+1)*64 + lane];
    c0 = __builtin_amdgcn_mfma_f32_32x32x16_bf16(a, bf0, c0, 0, 0, 0);
    c1 = __builtin_amdgcn_mfma_f32_32x32x16_bf16(a, bf1, c1, 0, 0, 0);
  }
  __builtin_amdgcn_s_setprio(0);

  const bool doG = (withG != 0);
  const int g0 = __shfl(g, 0), g31 = __shfl(g, 31);
  const bool uni = (g0 == g31);
  long long s0 = 0, s1 = 0;
  #pragma unroll
  for (int reg=0; reg<16; reg++){
    int row = (reg&3) + 8*(reg>>2) + 4*khalf;
    int gg = __shfl(g, row);
    int nn = n0 + row;
    if (nn < NN){
      size_t i0 = (size_t)nn*64 + r;
      float v0 = h32[i0] + c0[reg];
      float v1 = h32[i0+32] + c1[reg];
      h32[i0] = v0;    h16[i0] = f2b(v0);
      h32[i0+32] = v1; h16[i0+32] = f2b(v1);
      if (doG){
        long long q0 = llrintf(v0*SCALE_G), q1 = llrintf(v1*SCALE_G);
        if (uni){ s0 += q0; s1 += q1; }
        else {
          atomicAdd(&gs[gg*64 + r     ], (unsigned long long)q0);
          atomicAdd(&gs[gg*64 + 32 + r], (unsigned long long)q1);
        }
      }
    }
  }
  if (doG && uni && (s0|s1)){
    atomicAdd(&gs[g0*64 + r     ], (unsigned long long)s0);
    atomicAdd(&gs[g0*64 + 32 + r], (unsigned long long)s1);
  }
  __syncthreads();
  if (doG){
    for (int i=t; i<GG*64; i+=64){
      unsigned long long v = gs[i];
      if (v) atomicAdd(&xg_sum[i], v);
    }
  }
}

// ---------------- decoder ----------------
__global__ __launch_bounds__(256) void k_dec(
    const float* __restrict__ h,
    const float* __restrict__ w1, const float* __restrict__ b1,
    const float* __restrict__ w2, const float* __restrict__ b2,
    float* __restrict__ out){
  __shared__ float w1s[64*64];
  __shared__ float w2s[64*4];
  __shared__ float b1s[64], b2s[4];
  int t=threadIdx.x;
  for (int i=t;i<64*64;i+=256) w1s[i]=w1[i];
  for (int i=t;i<256;i+=256) w2s[i]=w2[i];
  if (t<64) b1s[t]=b1[t];
  if (t<4) b2s[t]=b2[t];
  __syncthreads();
  int n = blockIdx.x*256+t;
  if (n>=NN) return;
  float xr[64];
  #pragma unroll
  for (int k=0;k<16;k++){
    float4 v = ld4(h + (size_t)n*64 + k*4);
    xr[k*4+0]=v.x; xr[k*4+1]=v.y; xr[k*4+2]=v.z; xr[k*4+3]=v.w;
  }
  float a0=b2s[0],a1=b2s[1],a2=b2s[2],a3=b2s[3];
  for (int o=0;o<64;o++){
    float a=b1s[o];
    #pragma unroll
    for (int k=0;k<64;k++) a += xr[k]*w1s[k*64+o];
    a = fmaxf(a,0.f);
    a0 += a*w2s[o*4+0]; a1 += a*w2s[o*4+1]; a2 += a*w2s[o*4+2]; a3 += a*w2s[o*4+3];
  }
  out[(size_t)n*4+0]=a0; out[(size_t)n*4+1]=a1; out[(size_t)n*4+2]=a2; out[(size_t)n*4+3]=a3;
}

extern "C" void kernel_launch(void* const* d_in, const int* in_sizes, int n_in,
                              void* d_out, int out_size, void* d_ws, size_t ws_size,
                              hipStream_t stream){
  const float* x   = (const float*)d_in[0];
  const float* xm  = (const float*)d_in[1];
  const int*   ei  = (const int*)d_in[2];
  const float* ea  = (const float*)d_in[3];
  const int* batch = (const int*)d_in[5];
  const float* enc_w1=(const float*)d_in[6],  *enc_b1=(const float*)d_in[7];
  const float* enc_w2=(const float*)d_in[8],  *enc_b2=(const float*)d_in[9];
  const float* msg_w1=(const float*)d_in[10], *msg_b1=(const float*)d_in[11];
  const float* msg_w2=(const float*)d_in[12], *msg_b2=(const float*)d_in[13];
  const float* upd_w1=(const float*)d_in[14], *upd_b1=(const float*)d_in[15];
  const float* upd_w2=(const float*)d_in[16], *upd_b2=(const float*)d_in[17];
  const float* dec_w1=(const float*)d_in[18], *dec_b1=(const float*)d_in[19];
  const float* dec_w2=(const float*)d_in[20], *dec_b2=(const float*)d_in[21];
  const int* srcp = ei;
  const int* dstp = ei + EE;

  char* ws = (char*)d_ws;
  // layout: zero region [agg|cnt|xg_sum|xbc_sum|ncnt|bccnt] is contiguous -> single memset
  float* h32     = (float*)(ws + 0);             // 12,800,000
  int*   agg     = (int*)  (ws + 12800000);      // 12,800,000
  int*   cnt     = (int*)  (ws + 25600000);      //    200,000
  unsigned long long* xg_sum  = (unsigned long long*)(ws + 25800000);  // 4096
  unsigned long long* xbc_sum = (unsigned long long*)(ws + 25804096);  // 4096
  float* ncnt    = (float*)(ws + 25808192);      //        32
  float* bccnt   = (float*)(ws + 25808224);      //        32
  short* h16     = (short*)(ws + 25808256);      //  6,400,000
  float* inv     = (float*)(ws + 32208256);      //    200,000
  short* xg16    = (short*)(ws + 32408256);      //      1024
  short* xbc16   = (short*)(ws + 32409280);      //      1024
  short* mw1p    = (short*)(ws + 32410304);      //     18432
  short* mw2p    = (short*)(ws + 32428736);      //      8192
  short* uw1p    = (short*)(ws + 32436928);      //     32768
  short* uw2p    = (short*)(ws + 32469696);      //      8192
  int*   offs    = (int*)  (ws + 32477888);      //    200,000
  int*   srcs_s  = (int*)  (ws + 32677888);      //  2,000,896
  int*   dsts_s  = (int*)  (ws + 34678784);      //  2,000,896
  short* ea16s   = (short*)(ws + 36679680);      //  4,001,792
  int*   bsum    = (int*)  (ws + 40681472);      //       800
  int*   boff    = (int*)  (ws + 40682272);      //       800
  int*   perm    = (int*)  (ws + 40683072);      //  2,000,896
  const size_t WS_NEED_SORT = 42683968;
  const int useSort = (ws_size >= WS_NEED_SORT) ? 1 : 0;

  // single zero pass: agg + cnt + xg_sum + xbc_sum + ncnt + bccnt
  hipMemsetAsync(ws + 12800000, 0, 13008256, stream);
  k_wpack<<<34, 256, 0, stream>>>(msg_w1, msg_w2, upd_w1, upd_w2, mw1p, mw2p, uw1p, uw2p);
  k_count<<<(EE+255)/256, 256, 0, stream>>>(dstp, cnt);
  if (useSort){
    k_scanA<<<NB, 256, 0, stream>>>(cnt, bsum);
    k_scanB<<<1, 256, 0, stream>>>(bsum, boff);
    k_scanC_prep<<<NB, 256, 0, stream>>>(cnt, boff, offs, inv, batch, xm, ncnt, bccnt);
    k_scat1<<<(EE+255)/256, 256, 0, stream>>>(dstp, offs, perm);
    k_scat2<<<(EE+255)/256, 256, 0, stream>>>(perm, srcp, dstp, ea, srcs_s, dsts_s, ea16s);
  } else {
    k_prep<<<(NN+255)/256, 256, 0, stream>>>(cnt, inv, batch, xm, ncnt, bccnt);
  }
  k_enc<<<(NN+255)/256, 256, 0, stream>>>(x, xm, enc_w1, enc_b1, enc_w2, enc_b2, h32, h16);
  k_gred<<<512, 256, 0, stream>>>(h32, batch, xm, xg_sum, xbc_sum, 1);

  if (useSort){
    for (int rp=0; rp<4; rp++){
      // msg block 0 performs gfin (xg_sum from gred at rp=0, from upd(rp-1) after)
      k_msg_s<<<(EE+63)/64, 64, 0, stream>>>(h16, srcs_s, dsts_s, ea16s, mw1p, msg_b1, mw2p, msg_b2, agg,
                                             xg_sum, xbc_sum, ncnt, bccnt, xg16, xbc16, (rp==0)?1:0);
      int withG = (rp < 3) ? 1 : 0;
      k_upd<<<(NN+31)/32, 64, 0, stream>>>(h32, h16, agg, inv, batch, xg16, xbc16, uw1p, upd_b1, uw2p, upd_b2, xg_sum, withG);
    }
  } else {
    k_gfin<<<1, 512, 0, stream>>>(xg_sum, xbc_sum, ncnt, bccnt, xg16, xbc16, 1);
    for (int rp=0; rp<4; rp++){
      k_msg_atomic<<<(EE+255)/256, 256, 0, stream>>>(h16, srcp, dstp, ea, mw1p, msg_b1, mw2p, msg_b2, agg);
      int withG = (rp < 3) ? 1 : 0;
      k_upd<<<(NN+31)/32, 64, 0, stream>>>(h32, h16, agg, inv, batch, xg16, xbc16, uw1p, upd_b1, uw2p, upd_b2, xg_sum, withG);
      if (withG) k_gfin<<<1, 512, 0, stream>>>(xg_sum, xbc_sum, ncnt, bccnt, xg16, xbc16, 0);
    }
  }
  k_dec<<<(NN+255)/256, 256, 0, stream>>>(h32, dec_w1, dec_b1, dec_w2, dec_b2, (float*)d_out);
}

// Round 14
// 399.293 us; speedup vs baseline: 1.5062x; 1.0183x over previous
//
#include <hip/hip_runtime.h>
#include <hip/hip_bf16.h>

#define NN 50000
#define EE 500000
#define GG 8
#define NB 196   // (NN+255)/256

#define SCALE_A 65536.0f          // agg fixed-point scale (2^16)
#define INV_SCALE_A (1.0f/65536.0f)
#define SCALE_G 16777216.0f       // graph-sum fixed-point scale (2^24)
#define INV_SCALE_G (1.0f/16777216.0f)

using short8 = __attribute__((ext_vector_type(8))) short;   // 8 bf16 (4 VGPR)
using f32x16 = __attribute__((ext_vector_type(16))) float;  // 32x32 accumulator

__device__ __forceinline__ float4 ld4(const float* p){ return *reinterpret_cast<const float4*>(p); }

__device__ __forceinline__ short f2b(float f){
  union { __hip_bfloat16 b; short s; } u;
  u.b = __float2bfloat16(f);
  return u.s;
}

// ---------------- degree count ----------------
__global__ __launch_bounds__(256) void k_count(const int* __restrict__ dst, int* __restrict__ cnt){
  int e = blockIdx.x*256 + threadIdx.x;
  if (e < EE) atomicAdd(&cnt[dst[e]], 1);
}

// ---------------- hierarchical exclusive scan ----------------
__global__ __launch_bounds__(256) void k_scanA(const int* __restrict__ cnt, int* __restrict__ bsum){
  __shared__ int s[256];
  int t = threadIdx.x;
  int i = blockIdx.x*256 + t;
  s[t] = (i < NN) ? cnt[i] : 0;
  __syncthreads();
  for (int o=128;o>0;o>>=1){ if (t<o) s[t]+=s[t+o]; __syncthreads(); }
  if (t==0) bsum[blockIdx.x] = s[0];
}

__global__ __launch_bounds__(256) void k_scanB(const int* __restrict__ bsum, int* __restrict__ boff){
  __shared__ int s[256];
  int t = threadIdx.x;
  s[t] = (t < NB) ? bsum[t] : 0;
  __syncthreads();
  for (int o=1;o<256;o<<=1){
    int u = (t>=o) ? s[t-o] : 0;
    __syncthreads();
    s[t] += u;
    __syncthreads();
  }
  if (t < NB) boff[t] = (t==0) ? 0 : s[t-1];
}

// scanC fused with per-node prep (inv, ncnt, bccnt)
__global__ __launch_bounds__(256) void k_scanC_prep(const int* __restrict__ cnt, const int* __restrict__ boff,
                                               int* __restrict__ offs,
                                               float* __restrict__ inv, const int* __restrict__ batch,
                                               const float* __restrict__ xm,
                                               float* __restrict__ ncnt, float* __restrict__ bccnt){
  __shared__ int s[256];
  __shared__ float lc[GG], lb[GG];
  int t = threadIdx.x;
  int i = blockIdx.x*256 + t;
  if (t < GG){ lc[t]=0.f; lb[t]=0.f; }
  int v = (i < NN) ? cnt[i] : 0;
  s[t] = v;
  __syncthreads();
  for (int o=1;o<256;o<<=1){
    int u = (t>=o) ? s[t-o] : 0;
    __syncthreads();
    s[t] += u;
    __syncthreads();
  }
  if (i < NN){
    offs[i] = boff[blockIdx.x] + s[t] - v;
    inv[i] = 1.0f / fmaxf((float)v, 1.0f);
    int g = batch[i];
    atomicAdd(&lc[g], 1.0f);
    atomicAdd(&lb[g], xm[i*3+2]);
  }
  __syncthreads();
  if (t < GG){ atomicAdd(&ncnt[t], lc[t]); atomicAdd(&bccnt[t], lb[t]); }
}

// ---------------- standalone prep (fallback path only) ----------------
__global__ __launch_bounds__(256) void k_prep(const int* __restrict__ cnt, float* __restrict__ inv,
                       const int* __restrict__ batch, const float* __restrict__ xm,
                       float* __restrict__ ncnt, float* __restrict__ bccnt){
  __shared__ float lc[GG], lb[GG];
  int t = threadIdx.x;
  if (t < GG){ lc[t]=0.f; lb[t]=0.f; }
  __syncthreads();
  int i = blockIdx.x*256 + t;
  if (i < NN){
    inv[i] = 1.0f / fmaxf((float)cnt[i], 1.0f);
    int g = batch[i];
    atomicAdd(&lc[g], 1.0f);
    atomicAdd(&lb[g], xm[i*3+2]);
  }
  __syncthreads();
  if (t < GG){ atomicAdd(&ncnt[t], lc[t]); atomicAdd(&bccnt[t], lb[t]); }
}

// ---------------- sort phase 1: scatter only perm (4B) ----------------
__global__ __launch_bounds__(256) void k_scat1(const int* __restrict__ dst, int* __restrict__ offs,
                                               int* __restrict__ perm){
  int e = blockIdx.x*256 + threadIdx.x;
  if (e >= EE) return;
  int d = dst[e];
  int pos = atomicAdd(&offs[d], 1);
  perm[pos] = e;
}

// ---------------- sort phase 2: gather via perm, coalesced writes ----------------
__global__ __launch_bounds__(256) void k_scat2(const int* __restrict__ perm,
                                               const int* __restrict__ src, const int* __restrict__ dst,
                                               const float* __restrict__ ea,
                                               int* __restrict__ srcs_s, int* __restrict__ dsts_s,
                                               short* __restrict__ ea16){
  int i = blockIdx.x*256 + threadIdx.x;
  if (i >= EE) return;
  int e = perm[i];
  srcs_s[i] = src[e];
  dsts_s[i] = dst[e];
  int lo = ((int)(unsigned short)f2b(ea[(size_t)e*3+0])) |
           (((int)(unsigned short)f2b(ea[(size_t)e*3+1])) << 16);
  int hi = ((int)(unsigned short)f2b(ea[(size_t)e*3+2]));
  int2 v; v.x = lo; v.y = hi;
  *(int2*)(ea16 + (size_t)i*4) = v;
}

// ---------------- weight pack: fp32 [K][64] -> bf16 MFMA B-fragment order ----------------
__device__ __forceinline__ void packone(const float* __restrict__ w, int Kreal, int idx, short* __restrict__ out){
  int k = idx >> 6, n = idx & 63;
  float v = (k < Kreal) ? w[k*64 + n] : 0.f;
  int ks = k >> 4, kl = k & 15;
  int lane = (n & 31) + 32*(kl >> 3);
  int e = kl & 7;
  out[(ks*2 + (n>>5))*512 + lane*8 + e] = f2b(v);
}

__global__ __launch_bounds__(256) void k_wpack(
    const float* __restrict__ mw1, const float* __restrict__ mw2,
    const float* __restrict__ uw1, const float* __restrict__ uw2,
    short* __restrict__ mw1p, short* __restrict__ mw2p,
    short* __restrict__ uw1p, short* __restrict__ uw2p){
  int gid = blockIdx.x*256 + threadIdx.x;
  int stride = gridDim.x*256;
  for (int i=gid; i<144*64; i+=stride) packone(mw1, 131, i, mw1p);
  for (int i=gid; i<64*64;  i+=stride) packone(mw2, 64,  i, mw2p);
  for (int i=gid; i<256*64; i+=stride) packone(uw1, 256, i, uw1p);
  for (int i=gid; i<64*64;  i+=stride) packone(uw2, 64,  i, uw2p);
}

// ---------------- encoder: LDS-staged coalesced output ----------------
__global__ __launch_bounds__(256) void k_enc(
    const float* __restrict__ x, const float* __restrict__ xm,
    const float* __restrict__ w1, const float* __restrict__ b1,
    const float* __restrict__ w2, const float* __restrict__ b2,
    float* __restrict__ h, short* __restrict__ h16){
  __shared__ float w1s[8*64];
  __shared__ float w2s[64*64];
  __shared__ float b1s[64], b2s[64];
  __shared__ float ols[4][64][17];
  int t = threadIdx.x;
  for (int i=t;i<8*64;i+=256) w1s[i]=w1[i];
  for (int i=t;i<64*64;i+=256) w2s[i]=w2[i];
  if (t<64){ b1s[t]=b1[t]; b2s[t]=b2[t]; }
  __syncthreads();
  const int w = t >> 6, lane = t & 63;
  const int base_w = blockIdx.x*256 + w*64;
  const int n = base_w + lane;
  const int nc = (n < NN) ? n : (NN-1);
  float in[8];
  #pragma unroll
  for (int k=0;k<5;k++) in[k] = x[nc*5+k];
  #pragma unroll
  for (int k=0;k<3;k++) in[5+k] = xm[nc*3+k];
  float hid[64];
  #pragma unroll
  for (int o=0;o<64;o++){
    float a = b1s[o];
    #pragma unroll
    for (int k=0;k<8;k++) a += in[k]*w1s[k*64+o];
    hid[o] = fmaxf(a, 0.f);
  }
  for (int c=0;c<4;c++){
    float a[16];
    #pragma unroll
    for (int j=0;j<16;j++) a[j] = b2s[c*16+j];
    for (int k=0;k<64;k++){
      float hv = hid[k];
      #pragma unroll
      for (int j=0;j<16;j++) a[j] += hv * w2s[k*64 + c*16 + j];
    }
    #pragma unroll
    for (int j=0;j<16;j++) ols[w][lane][j] = a[j];
    __syncthreads();
    #pragma unroll
    for (int p=0;p<4;p++){
      int nd = p*16 + (lane>>2);
      int jj = lane & 3;
      int ng = base_w + nd;
      if (ng < NN){
        float4 v = make_float4(ols[w][nd][jj*4+0], ols[w][nd][jj*4+1],
                               ols[w][nd][jj*4+2], ols[w][nd][jj*4+3]);
        *(float4*)(h + (size_t)ng*64 + c*16 + jj*4) = v;
      }
    }
    #pragma unroll
    for (int p=0;p<2;p++){
      int nd = p*32 + (lane>>1);
      int jj = (lane & 1)*8;
      int ng = base_w + nd;
      if (ng < NN){
        short8 s;
        #pragma unroll
        for (int q=0;q<8;q++) s[q] = f2b(ols[w][nd][jj+q]);
        *(short8*)(h16 + (size_t)ng*64 + c*16 + jj) = s;
      }
    }
    __syncthreads();
  }
}

// ---------------- per-graph reductions (initial, withBC) ----------------
__global__ __launch_bounds__(256) void k_gred(
    const float* __restrict__ h, const int* __restrict__ batch,
    const float* __restrict__ xm,
    unsigned long long* __restrict__ xg_sum, unsigned long long* __restrict__ xbc_sum, int withBC){
  __shared__ float ls[4][GG][64];
  __shared__ float lb[4][GG][64];
  int t = threadIdx.x;
  int d = t & 63, grp = t >> 6;
  for (int g=0; g<GG; g++){ ls[grp][g][d]=0.f; lb[grp][g][d]=0.f; }
  __syncthreads();
  for (int i = blockIdx.x*4 + grp; i < NN; i += gridDim.x*4){
    int g = batch[i];
    float v = h[(size_t)i*64 + d];
    ls[grp][g][d] += v;
    if (withBC) lb[grp][g][d] += v * xm[i*3+2];
  }
  __syncthreads();
  if (t < 64){
    for (int g=0; g<GG; g++){
      float s = ls[0][g][d]+ls[1][g][d]+ls[2][g][d]+ls[3][g][d];
      atomicAdd(&xg_sum[g*64+d], (unsigned long long)(long long)llrintf(s*SCALE_G));
    }
  } else if (withBC && t < 128){
    int dd = t & 63;
    for (int g=0; g<GG; g++){
      float s = lb[0][g][dd]+lb[1][g][dd]+lb[2][g][dd]+lb[3][g][dd];
      atomicAdd(&xbc_sum[g*64+dd], (unsigned long long)(long long)llrintf(s*SCALE_G));
    }
  }
}

// standalone gfin (fallback path only); zeroes xg_sum after reading
__global__ void k_gfin(unsigned long long* __restrict__ xg_sum, const unsigned long long* __restrict__ xbc_sum,
                       const float* __restrict__ ncnt, const float* __restrict__ bccnt,
                       short* __restrict__ xg16, short* __restrict__ xbc16, int withBC){
  int t = threadIdx.x; // 512
  int g = t >> 6;
  float sg = (float)(long long)xg_sum[t] * INV_SCALE_G;
  xg16[t] = f2b(sg / fmaxf(ncnt[g], 1.f));
  xg_sum[t] = 0;
  if (withBC){
    float sb = (float)(long long)xbc_sum[t] * INV_SCALE_G;
    xbc16[t] = f2b(sb / fmaxf(bccnt[g], 1.f));
  }
}

// ---------------- message MLP via MFMA bf16 (1-wave blocks, in-loop loads, prefix-sum walk) ----------------
__global__ __launch_bounds__(64) void k_msg_s(
    const short* __restrict__ h16,
    const int* __restrict__ srcs_s, const int* __restrict__ dsts_s,
    const short* __restrict__ ea16,
    const short* __restrict__ w1p, const float* __restrict__ b1,
    const short* __restrict__ w2p, const float* __restrict__ b2,
    int* __restrict__ agg,
    unsigned long long* __restrict__ xg_sum, const unsigned long long* __restrict__ xbc_sum,
    const float* __restrict__ ncnt, const float* __restrict__ bccnt,
    short* __restrict__ xg16, short* __restrict__ xbc16, int withBC){
  __shared__ int buf[2304];   // 9216 B: hidT (short[64][72]) then msg (int[32][65])
  const int t = threadIdx.x;             // 0..63
  if (blockIdx.x == 0){
    for (int i=t; i<GG*64; i+=64){
      int g = i >> 6;
      float sg = (float)(long long)xg_sum[i] * INV_SCALE_G;
      xg16[i] = f2b(sg / fmaxf(ncnt[g], 1.f));
      xg_sum[i] = 0;
      if (withBC){
        float sb = (float)(long long)xbc_sum[i] * INV_SCALE_G;
        xbc16[i] = f2b(sb / fmaxf(bccnt[g], 1.f));
      }
    }
  }
  // bijective XCD-aware swizzle (m204)
  const int nwg = gridDim.x;
  const int q = nwg >> 3, rm = nwg & 7;
  const int xcd = blockIdx.x & 7, idx = blockIdx.x >> 3;
  const int wg = (xcd < rm ? xcd*(q+1) : rm*(q+1) + (xcd-rm)*q) + idx;
  const int base = wg * 64;

  const int lane = t;
  const int r = lane & 31, khalf = lane >> 5;
  const int slot = base + lane;
  const int dl = (slot < EE) ? dsts_s[slot] : -1;

  const int eA = base + r, eB = base + 32 + r;
  const bool vA = eA < EE, vB = eB < EE;
  const int sA = vA ? srcs_s[eA] : 0;
  const int sB = vB ? srcs_s[eB] : 0;
  int dA = __shfl(dl, r);        if (dA < 0) dA = 0;
  int dB = __shfl(dl, 32 + r);   if (dB < 0) dB = 0;

  float b1v0 = b1[r], b1v1 = b1[32 + r];
  f32x16 acc00, acc01, acc10, acc11;
  #pragma unroll
  for (int j=0;j<16;j++){ acc00[j]=b1v0; acc01[j]=b1v1; acc10[j]=b1v0; acc11[j]=b1v1; }

  const short8* w1f = (const short8*)w1p;
  #pragma unroll
  for (int ks=0; ks<9; ks++){
    short8 a0, a1;
    if (ks < 8){
      long offA, offB;
      if (ks < 4){
        offA = (long)sA*64 + ks*16 + khalf*8;
        offB = (long)sB*64 + ks*16 + khalf*8;
      } else {
        offA = (long)dA*64 + (ks-4)*16 + khalf*8;
        offB = (long)dB*64 + (ks-4)*16 + khalf*8;
      }
      a0 = *(const short8*)(h16 + offA);
      a1 = *(const short8*)(h16 + offB);
    } else {
      #pragma unroll
      for (int j=0;j<8;j++){ a0[j]=0; a1[j]=0; }
      if (khalf == 0){
        if (vA){
          int2 v = *(const int2*)(ea16 + (size_t)eA*4);
          a0[0]=(short)v.x; a0[1]=(short)(v.x>>16); a0[2]=(short)v.y; a0[3]=(short)(v.y>>16);
        }
        if (vB){
          int2 v = *(const int2*)(ea16 + (size_t)eB*4);
          a1[0]=(short)v.x; a1[1]=(short)(v.x>>16); a1[2]=(short)v.y; a1[3]=(short)(v.y>>16);
        }
      }
    }
    short8 bf0 = w1f[(ks*2+0)*64 + lane];
    short8 bf1 = w1f[(ks*2+1)*64 + lane];
    acc00 = __builtin_amdgcn_mfma_f32_32x32x16_bf16(a0, bf0, acc00, 0, 0, 0);
    acc01 = __builtin_amdgcn_mfma_f32_32x32x16_bf16(a0, bf1, acc01, 0, 0, 0);
    acc10 = __builtin_amdgcn_mfma_f32_32x32x16_bf16(a1, bf0, acc10, 0, 0, 0);
    acc11 = __builtin_amdgcn_mfma_f32_32x32x16_bf16(a1, bf1, acc11, 0, 0, 0);
  }

  short* hw = (short*)&buf[0];
  #pragma unroll
  for (int reg=0; reg<16; reg++){
    int row = (reg&3) + 8*(reg>>2) + 4*khalf;
    hw[(row     )*72 + r     ] = f2b(fmaxf(acc00[reg], 0.f));
    hw[(row     )*72 + 32 + r] = f2b(fmaxf(acc01[reg], 0.f));
    hw[(row + 32)*72 + r     ] = f2b(fmaxf(acc10[reg], 0.f));
    hw[(row + 32)*72 + 32 + r] = f2b(fmaxf(acc11[reg], 0.f));
  }

  float b2v0 = b2[r], b2v1 = b2[32 + r];
  f32x16 c00, c01, c10, c11;
  #pragma unroll
  for (int j=0;j<16;j++){ c00[j]=b2v0; c01[j]=b2v1; c10[j]=b2v0; c11[j]=b2v1; }

  const short8* w2f = (const short8*)w2p;
  #pragma unroll
  for (int ks=0; ks<4; ks++){
    short8 p0 = *(const short8*)(hw + (r     )*72 + ks*16 + khalf*8);
    short8 p1 = *(const short8*)(hw + (32 + r)*72 + ks*16 + khalf*8);
    short8 bf0 = w2f[(ks*2+0)*64 + lane];
    short8 bf1 = w2f[(ks*2+1)*64 + lane];
    c00 = __builtin_amdgcn_mfma_f32_32x32x16_bf16(p0, bf0, c00, 0, 0, 0);
    c01 = __builtin_amdgcn_mfma_f32_32x32x16_bf16(p0, bf1, c01, 0, 0, 0);
    c10 = __builtin_amdgcn_mfma_f32_32x32x16_bf16(p1, bf0, c10, 0, 0, 0);
    c11 = __builtin_amdgcn_mfma_f32_32x32x16_bf16(p1, bf1, c11, 0, 0, 0);
  }

  int* mb = &buf[0];

  // PASS A (slots base..base+31)
  #pragma unroll
  for (int reg=0; reg<16; reg++){
    int row = (reg&3) + 8*(reg>>2) + 4*khalf;
    mb[row*65 + r     ] = __float2int_rn(c00[reg]*SCALE_A);
    mb[row*65 + 32 + r] = __float2int_rn(c01[reg]*SCALE_A);
  }
  {
    int run = 0;
    #pragma unroll
    for (int rr=0; rr<32; rr++){ run += mb[rr*65 + lane]; mb[rr*65 + lane] = run; }
    int cur = 0;
    while (cur < 32){
      int d = __shfl(dl, cur);
      unsigned long long diff = __ballot(dl != d);
      unsigned low = (unsigned)diff;
      unsigned rest = low & (0xFFFFFFFEu << cur);
      int end = rest ? (__ffs(rest) - 1) : 32;
      if (d >= 0){
        int s = mb[(end-1)*65 + lane] - (cur ? mb[(cur-1)*65 + lane] : 0);
        atomicAdd(&agg[(size_t)d*64 + lane], s);
      }
      cur = end;
    }
  }

  // PASS B (slots base+32..base+63)
  #pragma unroll
  for (int reg=0; reg<16; reg++){
    int row = (reg&3) + 8*(reg>>2) + 4*khalf;
    mb[row*65 + r     ] = __float2int_rn(c10[reg]*SCALE_A);
    mb[row*65 + 32 + r] = __float2int_rn(c11[reg]*SCALE_A);
  }
  {
    int run = 0;
    #pragma unroll
    for (int rr=0; rr<32; rr++){ run += mb[rr*65 + lane]; mb[rr*65 + lane] = run; }
    int cur = 0;
    while (cur < 32){
      int d = __shfl(dl, 32 + cur);
      unsigned long long diff = __ballot(dl != d);
      unsigned hi = (unsigned)(diff >> 32);
      unsigned rest = hi & (0xFFFFFFFEu << cur);
      int end = rest ? (__ffs(rest) - 1) : 32;
      if (d >= 0){
        int s = mb[(end-1)*65 + lane] - (cur ? mb[(cur-1)*65 + lane] : 0);
        atomicAdd(&agg[(size_t)d*64 + lane], s);
      }
      cur = end;
    }
  }
}

// ---------------- fallback: per-edge atomic scatter ----------------
__global__ __launch_bounds__(256) void k_msg_atomic(
    const short* __restrict__ h16, const int* __restrict__ src, const int* __restrict__ dst,
    const float* __restrict__ ea,
    const short* __restrict__ w1p, const float* __restrict__ b1,
    const short* __restrict__ w2p, const float* __restrict__ b2,
    int* __restrict__ agg){
  __shared__ short hidT[4][64*72];
  const int t = threadIdx.x;
  const int w = t >> 6, lane = t & 63;
  const int r = lane & 31, khalf = lane >> 5;
  const int base = blockIdx.x*256 + w*64;
  const int eA = base + r, eB = base + 32 + r;
  const bool vA = eA < EE, vB = eB < EE;
  const int sA = vA ? src[eA] : 0, dA_ = vA ? dst[eA] : 0;
  const int sB = vB ? src[eB] : 0, dB_ = vB ? dst[eB] : 0;

  float b1v0 = b1[r], b1v1 = b1[32 + r];
  f32x16 acc00, acc01, acc10, acc11;
  #pragma unroll
  for (int j=0;j<16;j++){ acc00[j]=b1v0; acc01[j]=b1v1; acc10[j]=b1v0; acc11[j]=b1v1; }

  const short8* w1f = (const short8*)w1p;
  #pragma unroll
  for (int ks=0; ks<9; ks++){
    short8 a0, a1;
    if (ks < 8){
      long offA, offB;
      if (ks < 4){
        offA = (long)sA*64 + ks*16 + khalf*8;
        offB = (long)sB*64 + ks*16 + khalf*8;
      } else {
        offA = (long)dA_*64 + (ks-4)*16 + khalf*8;
        offB = (long)dB_*64 + (ks-4)*16 + khalf*8;
      }
      a0 = *(const short8*)(h16 + offA);
      a1 = *(const short8*)(h16 + offB);
    } else {
      #pragma unroll
      for (int j=0;j<8;j++){ a0[j]=0; a1[j]=0; }
      if (khalf == 0){
        if (vA){ a0[0]=f2b(ea[3*eA]); a0[1]=f2b(ea[3*eA+1]); a0[2]=f2b(ea[3*eA+2]); }
        if (vB){ a1[0]=f2b(ea[3*eB]); a1[1]=f2b(ea[3*eB+1]); a1[2]=f2b(ea[3*eB+2]); }
      }
    }
    short8 bf0 = w1f[(ks*2+0)*64 + lane];
    short8 bf1 = w1f[(ks*2+1)*64 + lane];
    acc00 = __builtin_amdgcn_mfma_f32_32x32x16_bf16(a0, bf0, acc00, 0, 0, 0);
    acc01 = __builtin_amdgcn_mfma_f32_32x32x16_bf16(a0, bf1, acc01, 0, 0, 0);
    acc10 = __builtin_amdgcn_mfma_f32_32x32x16_bf16(a1, bf0, acc10, 0, 0, 0);
    acc11 = __builtin_amdgcn_mfma_f32_32x32x16_bf16(a1, bf1, acc11, 0, 0, 0);
  }

  short* hw = &hidT[w][0];
  #pragma unroll
  for (int reg=0; reg<16; reg++){
    int row = (reg&3) + 8*(reg>>2) + 4*khalf;
    hw[(row     )*72 + r     ] = f2b(fmaxf(acc00[reg], 0.f));
    hw[(row     )*72 + 32 + r] = f2b(fmaxf(acc01[reg], 0.f));
    hw[(row + 32)*72 + r     ] = f2b(fmaxf(acc10[reg], 0.f));
    hw[(row + 32)*72 + 32 + r] = f2b(fmaxf(acc11[reg], 0.f));
  }

  float b2v0 = b2[r], b2v1 = b2[32 + r];
  f32x16 c00, c01, c10, c11;
  #pragma unroll
  for (int j=0;j<16;j++){ c00[j]=b2v0; c01[j]=b2v1; c10[j]=b2v0; c11[j]=b2v1; }

  const short8* w2f = (const short8*)w2p;
  #pragma unroll
  for (int ks=0; ks<4; ks++){
    short8 a0 = *(const short8*)(hw + (r     )*72 + ks*16 + khalf*8);
    short8 a1 = *(const short8*)(hw + (32 + r)*72 + ks*16 + khalf*8);
    short8 bf0 = w2f[(ks*2+0)*64 + lane];
    short8 bf1 = w2f[(ks*2+1)*64 + lane];
    c00 = __builtin_amdgcn_mfma_f32_32x32x16_bf16(a0, bf0, c00, 0, 0, 0);
    c01 = __builtin_amdgcn_mfma_f32_32x32x16_bf16(a0, bf1, c01, 0, 0, 0);
    c10 = __builtin_amdgcn_mfma_f32_32x32x16_bf16(a1, bf0, c10, 0, 0, 0);
    c11 = __builtin_amdgcn_mfma_f32_32x32x16_bf16(a1, bf1, c11, 0, 0, 0);
  }

  #pragma unroll
  for (int reg=0; reg<16; reg++){
    int row = (reg&3) + 8*(reg>>2) + 4*khalf;
    int e0r = base + row;
    int e1r = base + 32 + row;
    int d0 = __shfl(dA_, row);
    int d1 = __shfl(dB_, row);
    if (e0r < EE){
      atomicAdd(&agg[(size_t)d0*64 + r     ], __float2int_rn(c00[reg]*SCALE_A));
      atomicAdd(&agg[(size_t)d0*64 + 32 + r], __float2int_rn(c01[reg]*SCALE_A));
    }
    if (e1r < EE){
      atomicAdd(&agg[(size_t)d1*64 + r     ], __float2int_rn(c10[reg]*SCALE_A));
      atomicAdd(&agg[(size_t)d1*64 + 32 + r], __float2int_rn(c11[reg]*SCALE_A));
    }
  }
}

// ---------------- node update MLP (1-wave blocks), fused graph-reduction + agg re-zero ----------------
__global__ __launch_bounds__(64) void k_upd(
    float* __restrict__ h32, short* __restrict__ h16,
    int* __restrict__ agg, const float* __restrict__ inv,
    const int* __restrict__ batch,
    const short* __restrict__ xg16, const short* __restrict__ xbc16,
    const short* __restrict__ w1p, const float* __restrict__ b1,
    const short* __restrict__ w2p, const float* __restrict__ b2,
    unsigned long long* __restrict__ xg_sum, int withG){
  __shared__ short hidT[32*72];          // 4608 B
  __shared__ unsigned long long gs[GG*64]; // 4096 B
  const int t = threadIdx.x;             // 0..63
  for (int i=t; i<GG*64; i+=64) gs[i]=0;
  __syncthreads();

  const int lane = t;
  const int r = lane & 31, khalf = lane >> 5;
  const int n0 = blockIdx.x*32;
  const int n = n0 + r;
  const int nc = (n < NN) ? n : (NN-1);
  const int g = batch[nc];
  const float sc = inv[nc] * INV_SCALE_A;

  float b1v0 = b1[r], b1v1 = b1[32 + r];
  f32x16 a0acc, a1acc;
  #pragma unroll
  for (int j=0;j<16;j++){ a0acc[j]=b1v0; a1acc[j]=b1v1; }

  const short8* w1f = (const short8*)w1p;
  #pragma unroll
  for (int ks=0; ks<16; ks++){
    short8 a;
    int so = (ks & 3)*16 + khalf*8;
    if (ks < 4){
      a = *(const short8*)(h16 + (long)nc*64 + so);
    } else if (ks < 8){
      int4 i0 = *(const int4*)(agg + (long)nc*64 + so);
      int4 i1 = *(const int4*)(agg + (long)nc*64 + so + 4);
      if (n < NN){
        *(int4*)(agg + (long)nc*64 + so)     = make_int4(0,0,0,0);
        *(int4*)(agg + (long)nc*64 + so + 4) = make_int4(0,0,0,0);
      }
      a[0]=f2b((float)i0.x*sc); a[1]=f2b((float)i0.y*sc); a[2]=f2b((float)i0.z*sc); a[3]=f2b((float)i0.w*sc);
      a[4]=f2b((float)i1.x*sc); a[5]=f2b((float)i1.y*sc); a[6]=f2b((float)i1.z*sc); a[7]=f2b((float)i1.w*sc);
    } else if (ks < 12){
      a = *(const short8*)(xg16 + g*64 + so);
    } else {
      a = *(const short8*)(xbc16 + g*64 + so);
    }
    short8 bf0 = w1f[(ks*2+0)*64 + lane];
    short8 bf1 = w1f[(ks*2+1)*64 + lane];
    a0acc = __builtin_amdgcn_mfma_f32_32x32x16_bf16(a, bf0, a0acc, 0, 0, 0);
    a1acc = __builtin_amdgcn_mfma_f32_32x32x16_bf16(a, bf1, a1acc, 0, 0, 0);
  }

  short* hw = hidT;
  #pragma unroll
  for (int reg=0; reg<16; reg++){
    int row = (reg&3) + 8*(reg>>2) + 4*khalf;
    hw[row*72 + r     ] = f2b(fmaxf(a0acc[reg], 0.f));
    hw[row*72 + 32 + r] = f2b(fmaxf(a1acc[reg], 0.f));
  }

  float b2v0 = b2[r], b2v1 = b2[32 + r];
  f32x16 c0, c1;
  #pragma unroll
  for (int j=0;j<16;j++){ c0[j]=b2v0; c1[j]=b2v1; }

  const short8* w2f = (const short8*)w2p;
  #pragma unroll
  for (int ks=0; ks<4; ks++){
    short8 a = *(const short8*)(hw + r*72 + ks*16 + khalf*8);
    short8 bf0 = w2f[(ks*2+0)*64 + lane];
    short8 bf1 = w2f[(ks*2+1)*64 + lane];
    c0 = __builtin_amdgcn_mfma_f32_32x32x16_bf16(a, bf0, c0, 0, 0, 0);
    c1 = __builtin_amdgcn_mfma_f32_32x32x16_bf16(a, bf1, c1, 0, 0, 0);
  }

  const bool doG = (withG != 0);
  const int g0 = __shfl(g, 0), g31 = __shfl(g, 31);
  const bool uni = (g0 == g31);
  long long s0 = 0, s1 = 0;
  #pragma unroll
  for (int reg=0; reg<16; reg++){
    int row = (reg&3) + 8*(reg>>2) + 4*khalf;
    int gg = __shfl(g, row);
    int nn = n0 + row;
    if (nn < NN){
      size_t i0 = (size_t)nn*64 + r;
      float v0 = h32[i0] + c0[reg];
      float v1 = h32[i0+32] + c1[reg];
      h32[i0] = v0;
      h32[i0+32] = v1;
      if (doG){
        // h16 only consumed by next round's msg kernel; final round (withG==0) skips it
        h16[i0] = f2b(v0);
        h16[i0+32] = f2b(v1);
        long long q0 = llrintf(v0*SCALE_G), q1 = llrintf(v1*SCALE_G);
        if (uni){ s0 += q0; s1 += q1; }
        else {
          atomicAdd(&gs[gg*64 + r     ], (unsigned long long)q0);
          atomicAdd(&gs[gg*64 + 32 + r], (unsigned long long)q1);
        }
      }
    }
  }
  if (doG && uni && (s0|s1)){
    atomicAdd(&gs[g0*64 + r     ], (unsigned long long)s0);
    atomicAdd(&gs[g0*64 + 32 + r], (unsigned long long)s1);
  }
  __syncthreads();
  if (doG){
    for (int i=t; i<GG*64; i+=64){
      unsigned long long v = gs[i];
      if (v) atomicAdd(&xg_sum[i], v);
    }
  }
}

// ---------------- decoder ----------------
__global__ __launch_bounds__(256) void k_dec(
    const float* __restrict__ h,
    const float* __restrict__ w1, const float* __restrict__ b1,
    const float* __restrict__ w2, const float* __restrict__ b2,
    float* __restrict__ out){
  __shared__ float w1s[64*64];
  __shared__ float w2s[64*4];
  __shared__ float b1s[64], b2s[4];
  int t=threadIdx.x;
  for (int i=t;i<64*64;i+=256) w1s[i]=w1[i];
  for (int i=t;i<256;i+=256) w2s[i]=w2[i];
  if (t<64) b1s[t]=b1[t];
  if (t<4) b2s[t]=b2[t];
  __syncthreads();
  int n = blockIdx.x*256+t;
  if (n>=NN) return;
  float xr[64];
  #pragma unroll
  for (int k=0;k<16;k++){
    float4 v = ld4(h + (size_t)n*64 + k*4);
    xr[k*4+0]=v.x; xr[k*4+1]=v.y; xr[k*4+2]=v.z; xr[k*4+3]=v.w;
  }
  float a0=b2s[0],a1=b2s[1],a2=b2s[2],a3=b2s[3];
  for (int o=0;o<64;o++){
    float a=b1s[o];
    #pragma unroll
    for (int k=0;k<64;k++) a += xr[k]*w1s[k*64+o];
    a = fmaxf(a,0.f);
    a0 += a*w2s[o*4+0]; a1 += a*w2s[o*4+1]; a2 += a*w2s[o*4+2]; a3 += a*w2s[o*4+3];
  }
  out[(size_t)n*4+0]=a0; out[(size_t)n*4+1]=a1; out[(size_t)n*4+2]=a2; out[(size_t)n*4+3]=a3;
}

extern "C" void kernel_launch(void* const* d_in, const int* in_sizes, int n_in,
                              void* d_out, int out_size, void* d_ws, size_t ws_size,
                              hipStream_t stream){
  const float* x   = (const float*)d_in[0];
  const float* xm  = (const float*)d_in[1];
  const int*   ei  = (const int*)d_in[2];
  const float* ea  = (const float*)d_in[3];
  const int* batch = (const int*)d_in[5];
  const float* enc_w1=(const float*)d_in[6],  *enc_b1=(const float*)d_in[7];
  const float* enc_w2=(const float*)d_in[8],  *enc_b2=(const float*)d_in[9];
  const float* msg_w1=(const float*)d_in[10], *msg_b1=(const float*)d_in[11];
  const float* msg_w2=(const float*)d_in[12], *msg_b2=(const float*)d_in[13];
  const float* upd_w1=(const float*)d_in[14], *upd_b1=(const float*)d_in[15];
  const float* upd_w2=(const float*)d_in[16], *upd_b2=(const float*)d_in[17];
  const float* dec_w1=(const float*)d_in[18], *dec_b1=(const float*)d_in[19];
  const float* dec_w2=(const float*)d_in[20], *dec_b2=(const float*)d_in[21];
  const int* srcp = ei;
  const int* dstp = ei + EE;

  char* ws = (char*)d_ws;
  // layout: zero region [agg|cnt|xg_sum|xbc_sum|ncnt|bccnt] is contiguous -> single memset
  float* h32     = (float*)(ws + 0);             // 12,800,000
  int*   agg     = (int*)  (ws + 12800000);      // 12,800,000
  int*   cnt     = (int*)  (ws + 25600000);      //    200,000
  unsigned long long* xg_sum  = (unsigned long long*)(ws + 25800000);  // 4096
  unsigned long long* xbc_sum = (unsigned long long*)(ws + 25804096);  // 4096
  float* ncnt    = (float*)(ws + 25808192);      //        32
  float* bccnt   = (float*)(ws + 25808224);      //        32
  short* h16     = (short*)(ws + 25808256);      //  6,400,000
  float* inv     = (float*)(ws + 32208256);      //    200,000
  short* xg16    = (short*)(ws + 32408256);      //      1024
  short* xbc16   = (short*)(ws + 32409280);      //      1024
  short* mw1p    = (short*)(ws + 32410304);      //     18432
  short* mw2p    = (short*)(ws + 32428736);      //      8192
  short* uw1p    = (short*)(ws + 32436928);      //     32768
  short* uw2p    = (short*)(ws + 32469696);      //      8192
  int*   offs    = (int*)  (ws + 32477888);      //    200,000
  int*   srcs_s  = (int*)  (ws + 32677888);      //  2,000,896
  int*   dsts_s  = (int*)  (ws + 34678784);      //  2,000,896
  short* ea16s   = (short*)(ws + 36679680);      //  4,001,792
  int*   bsum    = (int*)  (ws + 40681472);      //       800
  int*   boff    = (int*)  (ws + 40682272);      //       800
  int*   perm    = (int*)  (ws + 40683072);      //  2,000,896
  const size_t WS_NEED_SORT = 42683968;
  const int useSort = (ws_size >= WS_NEED_SORT) ? 1 : 0;

  // single zero pass: agg + cnt + xg_sum + xbc_sum + ncnt + bccnt
  hipMemsetAsync(ws + 12800000, 0, 13008256, stream);
  k_wpack<<<34, 256, 0, stream>>>(msg_w1, msg_w2, upd_w1, upd_w2, mw1p, mw2p, uw1p, uw2p);
  k_count<<<(EE+255)/256, 256, 0, stream>>>(dstp, cnt);
  if (useSort){
    k_scanA<<<NB, 256, 0, stream>>>(cnt, bsum);
    k_scanB<<<1, 256, 0, stream>>>(bsum, boff);
    k_scanC_prep<<<NB, 256, 0, stream>>>(cnt, boff, offs, inv, batch, xm, ncnt, bccnt);
    k_scat1<<<(EE+255)/256, 256, 0, stream>>>(dstp, offs, perm);
    k_scat2<<<(EE+255)/256, 256, 0, stream>>>(perm, srcp, dstp, ea, srcs_s, dsts_s, ea16s);
  } else {
    k_prep<<<(NN+255)/256, 256, 0, stream>>>(cnt, inv, batch, xm, ncnt, bccnt);
  }
  k_enc<<<(NN+255)/256, 256, 0, stream>>>(x, xm, enc_w1, enc_b1, enc_w2, enc_b2, h32, h16);
  k_gred<<<512, 256, 0, stream>>>(h32, batch, xm, xg_sum, xbc_sum, 1);

  if (useSort){
    for (int rp=0; rp<4; rp++){
      // msg block 0 performs gfin (xg_sum from gred at rp=0, from upd(rp-1) after)
      k_msg_s<<<(EE+63)/64, 64, 0, stream>>>(h16, srcs_s, dsts_s, ea16s, mw1p, msg_b1, mw2p, msg_b2, agg,
                                             xg_sum, xbc_sum, ncnt, bccnt, xg16, xbc16, (rp==0)?1:0);
      int withG = (rp < 3) ? 1 : 0;
      k_upd<<<(NN+31)/32, 64, 0, stream>>>(h32, h16, agg, inv, batch, xg16, xbc16, uw1p, upd_b1, uw2p, upd_b2, xg_sum, withG);
    }
  } else {
    k_gfin<<<1, 512, 0, stream>>>(xg_sum, xbc_sum, ncnt, bccnt, xg16, xbc16, 1);
    for (int rp=0; rp<4; rp++){
      k_msg_atomic<<<(EE+255)/256, 256, 0, stream>>>(h16, srcp, dstp, ea, mw1p, msg_b1, mw2p, msg_b2, agg);
      // fallback keeps h16 writes every round (withG=1 for h16 purposes on rounds 0-2; round 3 also safe to skip)
      int withG = (rp < 3) ? 1 : 0;
      k_upd<<<(NN+31)/32, 64, 0, stream>>>(h32, h16, agg, inv, batch, xg16, xbc16, uw1p, upd_b1, uw2p, upd_b2, xg_sum, withG);
      if (withG) k_gfin<<<1, 512, 0, stream>>>(xg_sum, xbc_sum, ncnt, bccnt, xg16, xbc16, 0);
    }
  }
  k_dec<<<(NN+255)/256, 256, 0, stream>>>(h32, dec_w1, dec_b1, dec_w2, dec_b2, (float*)d_out);
}

// Round 15
// 398.656 us; speedup vs baseline: 1.5086x; 1.0016x over previous
//
#include <hip/hip_runtime.h>
#include <hip/hip_bf16.h>

#define NN 50000
#define EE 500000
#define GG 8
#define NB 196   // (NN+255)/256

#define SCALE_A 65536.0f          // agg fixed-point scale (2^16)
#define INV_SCALE_A (1.0f/65536.0f)
#define SCALE_G 16777216.0f       // graph-sum fixed-point scale (2^24)
#define INV_SCALE_G (1.0f/16777216.0f)

using short8 = __attribute__((ext_vector_type(8))) short;   // 8 bf16 (4 VGPR)
using f32x16 = __attribute__((ext_vector_type(16))) float;  // 32x32 accumulator

__device__ __forceinline__ float4 ld4(const float* p){ return *reinterpret_cast<const float4*>(p); }

__device__ __forceinline__ short f2b(float f){
  union { __hip_bfloat16 b; short s; } u;
  u.b = __float2bfloat16(f);
  return u.s;
}

// ---------------- fast zero (runtime fillBuffer uses a tiny grid for 13MB: 284 GB/s, 45us) ----------------
__global__ __launch_bounds__(256) void k_zero(int4* __restrict__ p, int n4){
  int i = blockIdx.x*256 + threadIdx.x;
  int stride = gridDim.x*256;
  for (; i < n4; i += stride) p[i] = make_int4(0,0,0,0);
}

// ---------------- degree count ----------------
__global__ __launch_bounds__(256) void k_count(const int* __restrict__ dst, int* __restrict__ cnt){
  int e = blockIdx.x*256 + threadIdx.x;
  if (e < EE) atomicAdd(&cnt[dst[e]], 1);
}

// ---------------- hierarchical exclusive scan ----------------
__global__ __launch_bounds__(256) void k_scanA(const int* __restrict__ cnt, int* __restrict__ bsum){
  __shared__ int s[256];
  int t = threadIdx.x;
  int i = blockIdx.x*256 + t;
  s[t] = (i < NN) ? cnt[i] : 0;
  __syncthreads();
  for (int o=128;o>0;o>>=1){ if (t<o) s[t]+=s[t+o]; __syncthreads(); }
  if (t==0) bsum[blockIdx.x] = s[0];
}

__global__ __launch_bounds__(256) void k_scanB(const int* __restrict__ bsum, int* __restrict__ boff){
  __shared__ int s[256];
  int t = threadIdx.x;
  s[t] = (t < NB) ? bsum[t] : 0;
  __syncthreads();
  for (int o=1;o<256;o<<=1){
    int u = (t>=o) ? s[t-o] : 0;
    __syncthreads();
    s[t] += u;
    __syncthreads();
  }
  if (t < NB) boff[t] = (t==0) ? 0 : s[t-1];
}

// scanC fused with per-node prep (inv, ncnt, bccnt)
__global__ __launch_bounds__(256) void k_scanC_prep(const int* __restrict__ cnt, const int* __restrict__ boff,
                                               int* __restrict__ offs,
                                               float* __restrict__ inv, const int* __restrict__ batch,
                                               const float* __restrict__ xm,
                                               float* __restrict__ ncnt, float* __restrict__ bccnt){
  __shared__ int s[256];
  __shared__ float lc[GG], lb[GG];
  int t = threadIdx.x;
  int i = blockIdx.x*256 + t;
  if (t < GG){ lc[t]=0.f; lb[t]=0.f; }
  int v = (i < NN) ? cnt[i] : 0;
  s[t] = v;
  __syncthreads();
  for (int o=1;o<256;o<<=1){
    int u = (t>=o) ? s[t-o] : 0;
    __syncthreads();
    s[t] += u;
    __syncthreads();
  }
  if (i < NN){
    offs[i] = boff[blockIdx.x] + s[t] - v;
    inv[i] = 1.0f / fmaxf((float)v, 1.0f);
    int g = batch[i];
    atomicAdd(&lc[g], 1.0f);
    atomicAdd(&lb[g], xm[i*3+2]);
  }
  __syncthreads();
  if (t < GG){ atomicAdd(&ncnt[t], lc[t]); atomicAdd(&bccnt[t], lb[t]); }
}

// ---------------- standalone prep (fallback path only) ----------------
__global__ __launch_bounds__(256) void k_prep(const int* __restrict__ cnt, float* __restrict__ inv,
                       const int* __restrict__ batch, const float* __restrict__ xm,
                       float* __restrict__ ncnt, float* __restrict__ bccnt){
  __shared__ float lc[GG], lb[GG];
  int t = threadIdx.x;
  if (t < GG){ lc[t]=0.f; lb[t]=0.f; }
  __syncthreads();
  int i = blockIdx.x*256 + t;
  if (i < NN){
    inv[i] = 1.0f / fmaxf((float)cnt[i], 1.0f);
    int g = batch[i];
    atomicAdd(&lc[g], 1.0f);
    atomicAdd(&lb[g], xm[i*3+2]);
  }
  __syncthreads();
  if (t < GG){ atomicAdd(&ncnt[t], lc[t]); atomicAdd(&bccnt[t], lb[t]); }
}

// ---------------- sort phase 1: scatter only perm (4B) ----------------
__global__ __launch_bounds__(256) void k_scat1(const int* __restrict__ dst, int* __restrict__ offs,
                                               int* __restrict__ perm){
  int e = blockIdx.x*256 + threadIdx.x;
  if (e >= EE) return;
  int d = dst[e];
  int pos = atomicAdd(&offs[d], 1);
  perm[pos] = e;
}

// ---------------- sort phase 2: gather via perm, coalesced writes ----------------
__global__ __launch_bounds__(256) void k_scat2(const int* __restrict__ perm,
                                               const int* __restrict__ src, const int* __restrict__ dst,
                                               const float* __restrict__ ea,
                                               int* __restrict__ srcs_s, int* __restrict__ dsts_s,
                                               short* __restrict__ ea16){
  int i = blockIdx.x*256 + threadIdx.x;
  if (i >= EE) return;
  int e = perm[i];
  srcs_s[i] = src[e];
  dsts_s[i] = dst[e];
  int lo = ((int)(unsigned short)f2b(ea[(size_t)e*3+0])) |
           (((int)(unsigned short)f2b(ea[(size_t)e*3+1])) << 16);
  int hi = ((int)(unsigned short)f2b(ea[(size_t)e*3+2]));
  int2 v; v.x = lo; v.y = hi;
  *(int2*)(ea16 + (size_t)i*4) = v;
}

// ---------------- weight pack: fp32 [K][64] -> bf16 MFMA B-fragment order ----------------
__device__ __forceinline__ void packone(const float* __restrict__ w, int Kreal, int idx, short* __restrict__ out){
  int k = idx >> 6, n = idx & 63;
  float v = (k < Kreal) ? w[k*64 + n] : 0.f;
  int ks = k >> 4, kl = k & 15;
  int lane = (n & 31) + 32*(kl >> 3);
  int e = kl & 7;
  out[(ks*2 + (n>>5))*512 + lane*8 + e] = f2b(v);
}

__global__ __launch_bounds__(256) void k_wpack(
    const float* __restrict__ mw1, const float* __restrict__ mw2,
    const float* __restrict__ uw1, const float* __restrict__ uw2,
    short* __restrict__ mw1p, short* __restrict__ mw2p,
    short* __restrict__ uw1p, short* __restrict__ uw2p){
  int gid = blockIdx.x*256 + threadIdx.x;
  int stride = gridDim.x*256;
  for (int i=gid; i<144*64; i+=stride) packone(mw1, 131, i, mw1p);
  for (int i=gid; i<64*64;  i+=stride) packone(mw2, 64,  i, mw2p);
  for (int i=gid; i<256*64; i+=stride) packone(uw1, 256, i, uw1p);
  for (int i=gid; i<64*64;  i+=stride) packone(uw2, 64,  i, uw2p);
}

// ---------------- encoder: LDS-staged coalesced output ----------------
__global__ __launch_bounds__(256) void k_enc(
    const float* __restrict__ x, const float* __restrict__ xm,
    const float* __restrict__ w1, const float* __restrict__ b1,
    const float* __restrict__ w2, const float* __restrict__ b2,
    float* __restrict__ h, short* __restrict__ h16){
  __shared__ float w1s[8*64];
  __shared__ float w2s[64*64];
  __shared__ float b1s[64], b2s[64];
  __shared__ float ols[4][64][17];
  int t = threadIdx.x;
  for (int i=t;i<8*64;i+=256) w1s[i]=w1[i];
  for (int i=t;i<64*64;i+=256) w2s[i]=w2[i];
  if (t<64){ b1s[t]=b1[t]; b2s[t]=b2[t]; }
  __syncthreads();
  const int w = t >> 6, lane = t & 63;
  const int base_w = blockIdx.x*256 + w*64;
  const int n = base_w + lane;
  const int nc = (n < NN) ? n : (NN-1);
  float in[8];
  #pragma unroll
  for (int k=0;k<5;k++) in[k] = x[nc*5+k];
  #pragma unroll
  for (int k=0;k<3;k++) in[5+k] = xm[nc*3+k];
  float hid[64];
  #pragma unroll
  for (int o=0;o<64;o++){
    float a = b1s[o];
    #pragma unroll
    for (int k=0;k<8;k++) a += in[k]*w1s[k*64+o];
    hid[o] = fmaxf(a, 0.f);
  }
  for (int c=0;c<4;c++){
    float a[16];
    #pragma unroll
    for (int j=0;j<16;j++) a[j] = b2s[c*16+j];
    for (int k=0;k<64;k++){
      float hv = hid[k];
      #pragma unroll
      for (int j=0;j<16;j++) a[j] += hv * w2s[k*64 + c*16 + j];
    }
    #pragma unroll
    for (int j=0;j<16;j++) ols[w][lane][j] = a[j];
    __syncthreads();
    #pragma unroll
    for (int p=0;p<4;p++){
      int nd = p*16 + (lane>>2);
      int jj = lane & 3;
      int ng = base_w + nd;
      if (ng < NN){
        float4 v = make_float4(ols[w][nd][jj*4+0], ols[w][nd][jj*4+1],
                               ols[w][nd][jj*4+2], ols[w][nd][jj*4+3]);
        *(float4*)(h + (size_t)ng*64 + c*16 + jj*4) = v;
      }
    }
    #pragma unroll
    for (int p=0;p<2;p++){
      int nd = p*32 + (lane>>1);
      int jj = (lane & 1)*8;
      int ng = base_w + nd;
      if (ng < NN){
        short8 s;
        #pragma unroll
        for (int q=0;q<8;q++) s[q] = f2b(ols[w][nd][jj+q]);
        *(short8*)(h16 + (size_t)ng*64 + c*16 + jj) = s;
      }
    }
    __syncthreads();
  }
}

// ---------------- per-graph reductions (initial, withBC) ----------------
__global__ __launch_bounds__(256) void k_gred(
    const float* __restrict__ h, const int* __restrict__ batch,
    const float* __restrict__ xm,
    unsigned long long* __restrict__ xg_sum, unsigned long long* __restrict__ xbc_sum, int withBC){
  __shared__ float ls[4][GG][64];
  __shared__ float lb[4][GG][64];
  int t = threadIdx.x;
  int d = t & 63, grp = t >> 6;
  for (int g=0; g<GG; g++){ ls[grp][g][d]=0.f; lb[grp][g][d]=0.f; }
  __syncthreads();
  for (int i = blockIdx.x*4 + grp; i < NN; i += gridDim.x*4){
    int g = batch[i];
    float v = h[(size_t)i*64 + d];
    ls[grp][g][d] += v;
    if (withBC) lb[grp][g][d] += v * xm[i*3+2];
  }
  __syncthreads();
  if (t < 64){
    for (int g=0; g<GG; g++){
      float s = ls[0][g][d]+ls[1][g][d]+ls[2][g][d]+ls[3][g][d];
      atomicAdd(&xg_sum[g*64+d], (unsigned long long)(long long)llrintf(s*SCALE_G));
    }
  } else if (withBC && t < 128){
    int dd = t & 63;
    for (int g=0; g<GG; g++){
      float s = lb[0][g][dd]+lb[1][g][dd]+lb[2][g][dd]+lb[3][g][dd];
      atomicAdd(&xbc_sum[g*64+dd], (unsigned long long)(long long)llrintf(s*SCALE_G));
    }
  }
}

// standalone gfin (fallback path only); zeroes xg_sum after reading
__global__ void k_gfin(unsigned long long* __restrict__ xg_sum, const unsigned long long* __restrict__ xbc_sum,
                       const float* __restrict__ ncnt, const float* __restrict__ bccnt,
                       short* __restrict__ xg16, short* __restrict__ xbc16, int withBC){
  int t = threadIdx.x; // 512
  int g = t >> 6;
  float sg = (float)(long long)xg_sum[t] * INV_SCALE_G;
  xg16[t] = f2b(sg / fmaxf(ncnt[g], 1.f));
  xg_sum[t] = 0;
  if (withBC){
    float sb = (float)(long long)xbc_sum[t] * INV_SCALE_G;
    xbc16[t] = f2b(sb / fmaxf(bccnt[g], 1.f));
  }
}

// ---------------- message MLP via MFMA bf16 (1-wave blocks, in-loop loads, prefix-sum walk) ----------------
__global__ __launch_bounds__(64) void k_msg_s(
    const short* __restrict__ h16,
    const int* __restrict__ srcs_s, const int* __restrict__ dsts_s,
    const short* __restrict__ ea16,
    const short* __restrict__ w1p, const float* __restrict__ b1,
    const short* __restrict__ w2p, const float* __restrict__ b2,
    int* __restrict__ agg,
    unsigned long long* __restrict__ xg_sum, const unsigned long long* __restrict__ xbc_sum,
    const float* __restrict__ ncnt, const float* __restrict__ bccnt,
    short* __restrict__ xg16, short* __restrict__ xbc16, int withBC){
  __shared__ int buf[2304];   // 9216 B: hidT (short[64][72]) then msg (int[32][65])
  const int t = threadIdx.x;             // 0..63
  if (blockIdx.x == 0){
    for (int i=t; i<GG*64; i+=64){
      int g = i >> 6;
      float sg = (float)(long long)xg_sum[i] * INV_SCALE_G;
      xg16[i] = f2b(sg / fmaxf(ncnt[g], 1.f));
      xg_sum[i] = 0;
      if (withBC){
        float sb = (float)(long long)xbc_sum[i] * INV_SCALE_G;
        xbc16[i] = f2b(sb / fmaxf(bccnt[g], 1.f));
      }
    }
  }
  // bijective XCD-aware swizzle (m204)
  const int nwg = gridDim.x;
  const int q = nwg >> 3, rm = nwg & 7;
  const int xcd = blockIdx.x & 7, idx = blockIdx.x >> 3;
  const int wg = (xcd < rm ? xcd*(q+1) : rm*(q+1) + (xcd-rm)*q) + idx;
  const int base = wg * 64;

  const int lane = t;
  const int r = lane & 31, khalf = lane >> 5;
  const int slot = base + lane;
  const int dl = (slot < EE) ? dsts_s[slot] : -1;

  const int eA = base + r, eB = base + 32 + r;
  const bool vA = eA < EE, vB = eB < EE;
  const int sA = vA ? srcs_s[eA] : 0;
  const int sB = vB ? srcs_s[eB] : 0;
  int dA = __shfl(dl, r);        if (dA < 0) dA = 0;
  int dB = __shfl(dl, 32 + r);   if (dB < 0) dB = 0;

  float b1v0 = b1[r], b1v1 = b1[32 + r];
  f32x16 acc00, acc01, acc10, acc11;
  #pragma unroll
  for (int j=0;j<16;j++){ acc00[j]=b1v0; acc01[j]=b1v1; acc10[j]=b1v0; acc11[j]=b1v1; }

  const short8* w1f = (const short8*)w1p;
  #pragma unroll
  for (int ks=0; ks<9; ks++){
    short8 a0, a1;
    if (ks < 8){
      long offA, offB;
      if (ks < 4){
        offA = (long)sA*64 + ks*16 + khalf*8;
        offB = (long)sB*64 + ks*16 + khalf*8;
      } else {
        offA = (long)dA*64 + (ks-4)*16 + khalf*8;
        offB = (long)dB*64 + (ks-4)*16 + khalf*8;
      }
      a0 = *(const short8*)(h16 + offA);
      a1 = *(const short8*)(h16 + offB);
    } else {
      #pragma unroll
      for (int j=0;j<8;j++){ a0[j]=0; a1[j]=0; }
      if (khalf == 0){
        if (vA){
          int2 v = *(const int2*)(ea16 + (size_t)eA*4);
          a0[0]=(short)v.x; a0[1]=(short)(v.x>>16); a0[2]=(short)v.y; a0[3]=(short)(v.y>>16);
        }
        if (vB){
          int2 v = *(const int2*)(ea16 + (size_t)eB*4);
          a1[0]=(short)v.x; a1[1]=(short)(v.x>>16); a1[2]=(short)v.y; a1[3]=(short)(v.y>>16);
        }
      }
    }
    short8 bf0 = w1f[(ks*2+0)*64 + lane];
    short8 bf1 = w1f[(ks*2+1)*64 + lane];
    acc00 = __builtin_amdgcn_mfma_f32_32x32x16_bf16(a0, bf0, acc00, 0, 0, 0);
    acc01 = __builtin_amdgcn_mfma_f32_32x32x16_bf16(a0, bf1, acc01, 0, 0, 0);
    acc10 = __builtin_amdgcn_mfma_f32_32x32x16_bf16(a1, bf0, acc10, 0, 0, 0);
    acc11 = __builtin_amdgcn_mfma_f32_32x32x16_bf16(a1, bf1, acc11, 0, 0, 0);
  }

  short* hw = (short*)&buf[0];
  #pragma unroll
  for (int reg=0; reg<16; reg++){
    int row = (reg&3) + 8*(reg>>2) + 4*khalf;
    hw[(row     )*72 + r     ] = f2b(fmaxf(acc00[reg], 0.f));
    hw[(row     )*72 + 32 + r] = f2b(fmaxf(acc01[reg], 0.f));
    hw[(row + 32)*72 + r     ] = f2b(fmaxf(acc10[reg], 0.f));
    hw[(row + 32)*72 + 32 + r] = f2b(fmaxf(acc11[reg], 0.f));
  }

  float b2v0 = b2[r], b2v1 = b2[32 + r];
  f32x16 c00, c01, c10, c11;
  #pragma unroll
  for (int j=0;j<16;j++){ c00[j]=b2v0; c01[j]=b2v1; c10[j]=b2v0; c11[j]=b2v1; }

  const short8* w2f = (const short8*)w2p;
  #pragma unroll
  for (int ks=0; ks<4; ks++){
    short8 p0 = *(const short8*)(hw + (r     )*72 + ks*16 + khalf*8);
    short8 p1 = *(const short8*)(hw + (32 + r)*72 + ks*16 + khalf*8);
    short8 bf0 = w2f[(ks*2+0)*64 + lane];
    short8 bf1 = w2f[(ks*2+1)*64 + lane];
    c00 = __builtin_amdgcn_mfma_f32_32x32x16_bf16(p0, bf0, c00, 0, 0, 0);
    c01 = __builtin_amdgcn_mfma_f32_32x32x16_bf16(p0, bf1, c01, 0, 0, 0);
    c10 = __builtin_amdgcn_mfma_f32_32x32x16_bf16(p1, bf0, c10, 0, 0, 0);
    c11 = __builtin_amdgcn_mfma_f32_32x32x16_bf16(p1, bf1, c11, 0, 0, 0);
  }

  int* mb = &buf[0];

  // PASS A (slots base..base+31)
  #pragma unroll
  for (int reg=0; reg<16; reg++){
    int row = (reg&3) + 8*(reg>>2) + 4*khalf;
    mb[row*65 + r     ] = __float2int_rn(c00[reg]*SCALE_A);
    mb[row*65 + 32 + r] = __float2int_rn(c01[reg]*SCALE_A);
  }
  {
    int run = 0;
    #pragma unroll
    for (int rr=0; rr<32; rr++){ run += mb[rr*65 + lane]; mb[rr*65 + lane] = run; }
    int cur = 0;
    while (cur < 32){
      int d = __shfl(dl, cur);
      unsigned long long diff = __ballot(dl != d);
      unsigned low = (unsigned)diff;
      unsigned rest = low & (0xFFFFFFFEu << cur);
      int end = rest ? (__ffs(rest) - 1) : 32;
      if (d >= 0){
        int s = mb[(end-1)*65 + lane] - (cur ? mb[(cur-1)*65 + lane] : 0);
        atomicAdd(&agg[(size_t)d*64 + lane], s);
      }
      cur = end;
    }
  }

  // PASS B (slots base+32..base+63)
  #pragma unroll
  for (int reg=0; reg<16; reg++){
    int row = (reg&3) + 8*(reg>>2) + 4*khalf;
    mb[row*65 + r     ] = __float2int_rn(c10[reg]*SCALE_A);
    mb[row*65 + 32 + r] = __float2int_rn(c11[reg]*SCALE_A);
  }
  {
    int run = 0;
    #pragma unroll
    for (int rr=0; rr<32; rr++){ run += mb[rr*65 + lane]; mb[rr*65 + lane] = run; }
    int cur = 0;
    while (cur < 32){
      int d = __shfl(dl, 32 + cur);
      unsigned long long diff = __ballot(dl != d);
      unsigned hi = (unsigned)(diff >> 32);
      unsigned rest = hi & (0xFFFFFFFEu << cur);
      int end = rest ? (__ffs(rest) - 1) : 32;
      if (d >= 0){
        int s = mb[(end-1)*65 + lane] - (cur ? mb[(cur-1)*65 + lane] : 0);
        atomicAdd(&agg[(size_t)d*64 + lane], s);
      }
      cur = end;
    }
  }
}

// ---------------- fallback: per-edge atomic scatter ----------------
__global__ __launch_bounds__(256) void k_msg_atomic(
    const short* __restrict__ h16, const int* __restrict__ src, const int* __restrict__ dst,
    const float* __restrict__ ea,
    const short* __restrict__ w1p, const float* __restrict__ b1,
    const short* __restrict__ w2p, const float* __restrict__ b2,
    int* __restrict__ agg){
  __shared__ short hidT[4][64*72];
  const int t = threadIdx.x;
  const int w = t >> 6, lane = t & 63;
  const int r = lane & 31, khalf = lane >> 5;
  const int base = blockIdx.x*256 + w*64;
  const int eA = base + r, eB = base + 32 + r;
  const bool vA = eA < EE, vB = eB < EE;
  const int sA = vA ? src[eA] : 0, dA_ = vA ? dst[eA] : 0;
  const int sB = vB ? src[eB] : 0, dB_ = vB ? dst[eB] : 0;

  float b1v0 = b1[r], b1v1 = b1[32 + r];
  f32x16 acc00, acc01, acc10, acc11;
  #pragma unroll
  for (int j=0;j<16;j++){ acc00[j]=b1v0; acc01[j]=b1v1; acc10[j]=b1v0; acc11[j]=b1v1; }

  const short8* w1f = (const short8*)w1p;
  #pragma unroll
  for (int ks=0; ks<9; ks++){
    short8 a0, a1;
    if (ks < 8){
      long offA, offB;
      if (ks < 4){
        offA = (long)sA*64 + ks*16 + khalf*8;
        offB = (long)sB*64 + ks*16 + khalf*8;
      } else {
        offA = (long)dA_*64 + (ks-4)*16 + khalf*8;
        offB = (long)dB_*64 + (ks-4)*16 + khalf*8;
      }
      a0 = *(const short8*)(h16 + offA);
      a1 = *(const short8*)(h16 + offB);
    } else {
      #pragma unroll
      for (int j=0;j<8;j++){ a0[j]=0; a1[j]=0; }
      if (khalf == 0){
        if (vA){ a0[0]=f2b(ea[3*eA]); a0[1]=f2b(ea[3*eA+1]); a0[2]=f2b(ea[3*eA+2]); }
        if (vB){ a1[0]=f2b(ea[3*eB]); a1[1]=f2b(ea[3*eB+1]); a1[2]=f2b(ea[3*eB+2]); }
      }
    }
    short8 bf0 = w1f[(ks*2+0)*64 + lane];
    short8 bf1 = w1f[(ks*2+1)*64 + lane];
    acc00 = __builtin_amdgcn_mfma_f32_32x32x16_bf16(a0, bf0, acc00, 0, 0, 0);
    acc01 = __builtin_amdgcn_mfma_f32_32x32x16_bf16(a0, bf1, acc01, 0, 0, 0);
    acc10 = __builtin_amdgcn_mfma_f32_32x32x16_bf16(a1, bf0, acc10, 0, 0, 0);
    acc11 = __builtin_amdgcn_mfma_f32_32x32x16_bf16(a1, bf1, acc11, 0, 0, 0);
  }

  short* hw = &hidT[w][0];
  #pragma unroll
  for (int reg=0; reg<16; reg++){
    int row = (reg&3) + 8*(reg>>2) + 4*khalf;
    hw[(row     )*72 + r     ] = f2b(fmaxf(acc00[reg], 0.f));
    hw[(row     )*72 + 32 + r] = f2b(fmaxf(acc01[reg], 0.f));
    hw[(row + 32)*72 + r     ] = f2b(fmaxf(acc10[reg], 0.f));
    hw[(row + 32)*72 + 32 + r] = f2b(fmaxf(acc11[reg], 0.f));
  }

  float b2v0 = b2[r], b2v1 = b2[32 + r];
  f32x16 c00, c01, c10, c11;
  #pragma unroll
  for (int j=0;j<16;j++){ c00[j]=b2v0; c01[j]=b2v1; c10[j]=b2v0; c11[j]=b2v1; }

  const short8* w2f = (const short8*)w2p;
  #pragma unroll
  for (int ks=0; ks<4; ks++){
    short8 a0 = *(const short8*)(hw + (r     )*72 + ks*16 + khalf*8);
    short8 a1 = *(const short8*)(hw + (32 + r)*72 + ks*16 + khalf*8);
    short8 bf0 = w2f[(ks*2+0)*64 + lane];
    short8 bf1 = w2f[(ks*2+1)*64 + lane];
    c00 = __builtin_amdgcn_mfma_f32_32x32x16_bf16(a0, bf0, c00, 0, 0, 0);
    c01 = __builtin_amdgcn_mfma_f32_32x32x16_bf16(a0, bf1, c01, 0, 0, 0);
    c10 = __builtin_amdgcn_mfma_f32_32x32x16_bf16(a1, bf0, c10, 0, 0, 0);
    c11 = __builtin_amdgcn_mfma_f32_32x32x16_bf16(a1, bf1, c11, 0, 0, 0);
  }

  #pragma unroll
  for (int reg=0; reg<16; reg++){
    int row = (reg&3) + 8*(reg>>2) + 4*khalf;
    int e0r = base + row;
    int e1r = base + 32 + row;
    int d0 = __shfl(dA_, row);
    int d1 = __shfl(dB_, row);
    if (e0r < EE){
      atomicAdd(&agg[(size_t)d0*64 + r     ], __float2int_rn(c00[reg]*SCALE_A));
      atomicAdd(&agg[(size_t)d0*64 + 32 + r], __float2int_rn(c01[reg]*SCALE_A));
    }
    if (e1r < EE){
      atomicAdd(&agg[(size_t)d1*64 + r     ], __float2int_rn(c10[reg]*SCALE_A));
      atomicAdd(&agg[(size_t)d1*64 + 32 + r], __float2int_rn(c11[reg]*SCALE_A));
    }
  }
}

// ---------------- node update MLP (1-wave blocks), fused graph-reduction + agg re-zero ----------------
__global__ __launch_bounds__(64) void k_upd(
    float* __restrict__ h32, short* __restrict__ h16,
    int* __restrict__ agg, const float* __restrict__ inv,
    const int* __restrict__ batch,
    const short* __restrict__ xg16, const short* __restrict__ xbc16,
    const short* __restrict__ w1p, const float* __restrict__ b1,
    const short* __restrict__ w2p, const float* __restrict__ b2,
    unsigned long long* __restrict__ xg_sum, int withG){
  __shared__ short hidT[32*72];          // 4608 B
  __shared__ unsigned long long gs[GG*64]; // 4096 B
  const int t = threadIdx.x;             // 0..63
  for (int i=t; i<GG*64; i+=64) gs[i]=0;
  __syncthreads();

  const int lane = t;
  const int r = lane & 31, khalf = lane >> 5;
  const int n0 = blockIdx.x*32;
  const int n = n0 + r;
  const int nc = (n < NN) ? n : (NN-1);
  const int g = batch[nc];
  const float sc = inv[nc] * INV_SCALE_A;

  float b1v0 = b1[r], b1v1 = b1[32 + r];
  f32x16 a0acc, a1acc;
  #pragma unroll
  for (int j=0;j<16;j++){ a0acc[j]=b1v0; a1acc[j]=b1v1; }

  const short8* w1f = (const short8*)w1p;
  #pragma unroll
  for (int ks=0; ks<16; ks++){
    short8 a;
    int so = (ks & 3)*16 + khalf*8;
    if (ks < 4){
      a = *(const short8*)(h16 + (long)nc*64 + so);
    } else if (ks < 8){
      int4 i0 = *(const int4*)(agg + (long)nc*64 + so);
      int4 i1 = *(const int4*)(agg + (long)nc*64 + so + 4);
      if (n < NN){
        *(int4*)(agg + (long)nc*64 + so)     = make_int4(0,0,0,0);
        *(int4*)(agg + (long)nc*64 + so + 4) = make_int4(0,0,0,0);
      }
      a[0]=f2b((float)i0.x*sc); a[1]=f2b((float)i0.y*sc); a[2]=f2b((float)i0.z*sc); a[3]=f2b((float)i0.w*sc);
      a[4]=f2b((float)i1.x*sc); a[5]=f2b((float)i1.y*sc); a[6]=f2b((float)i1.z*sc); a[7]=f2b((float)i1.w*sc);
    } else if (ks < 12){
      a = *(const short8*)(xg16 + g*64 + so);
    } else {
      a = *(const short8*)(xbc16 + g*64 + so);
    }
    short8 bf0 = w1f[(ks*2+0)*64 + lane];
    short8 bf1 = w1f[(ks*2+1)*64 + lane];
    a0acc = __builtin_amdgcn_mfma_f32_32x32x16_bf16(a, bf0, a0acc, 0, 0, 0);
    a1acc = __builtin_amdgcn_mfma_f32_32x32x16_bf16(a, bf1, a1acc, 0, 0, 0);
  }

  short* hw = hidT;
  #pragma unroll
  for (int reg=0; reg<16; reg++){
    int row = (reg&3) + 8*(reg>>2) + 4*khalf;
    hw[row*72 + r     ] = f2b(fmaxf(a0acc[reg], 0.f));
    hw[row*72 + 32 + r] = f2b(fmaxf(a1acc[reg], 0.f));
  }

  float b2v0 = b2[r], b2v1 = b2[32 + r];
  f32x16 c0, c1;
  #pragma unroll
  for (int j=0;j<16;j++){ c0[j]=b2v0; c1[j]=b2v1; }

  const short8* w2f = (const short8*)w2p;
  #pragma unroll
  for (int ks=0; ks<4; ks++){
    short8 a = *(const short8*)(hw + r*72 + ks*16 + khalf*8);
    short8 bf0 = w2f[(ks*2+0)*64 + lane];
    short8 bf1 = w2f[(ks*2+1)*64 + lane];
    c0 = __builtin_amdgcn_mfma_f32_32x32x16_bf16(a, bf0, c0, 0, 0, 0);
    c1 = __builtin_amdgcn_mfma_f32_32x32x16_bf16(a, bf1, c1, 0, 0, 0);
  }

  const bool doG = (withG != 0);
  const int g0 = __shfl(g, 0), g31 = __shfl(g, 31);
  const bool uni = (g0 == g31);
  long long s0 = 0, s1 = 0;
  #pragma unroll
  for (int reg=0; reg<16; reg++){
    int row = (reg&3) + 8*(reg>>2) + 4*khalf;
    int gg = __shfl(g, row);
    int nn = n0 + row;
    if (nn < NN){
      size_t i0 = (size_t)nn*64 + r;
      float v0 = h32[i0] + c0[reg];
      float v1 = h32[i0+32] + c1[reg];
      h32[i0] = v0;
      h32[i0+32] = v1;
      if (doG){
        // h16 only consumed by next round's msg kernel; final round (withG==0) skips it
        h16[i0] = f2b(v0);
        h16[i0+32] = f2b(v1);
        long long q0 = llrintf(v0*SCALE_G), q1 = llrintf(v1*SCALE_G);
        if (uni){ s0 += q0; s1 += q1; }
        else {
          atomicAdd(&gs[gg*64 + r     ], (unsigned long long)q0);
          atomicAdd(&gs[gg*64 + 32 + r], (unsigned long long)q1);
        }
      }
    }
  }
  if (doG && uni && (s0|s1)){
    atomicAdd(&gs[g0*64 + r     ], (unsigned long long)s0);
    atomicAdd(&gs[g0*64 + 32 + r], (unsigned long long)s1);
  }
  __syncthreads();
  if (doG){
    for (int i=t; i<GG*64; i+=64){
      unsigned long long v = gs[i];
      if (v) atomicAdd(&xg_sum[i], v);
    }
  }
}

// ---------------- decoder ----------------
__global__ __launch_bounds__(256) void k_dec(
    const float* __restrict__ h,
    const float* __restrict__ w1, const float* __restrict__ b1,
    const float* __restrict__ w2, const float* __restrict__ b2,
    float* __restrict__ out){
  __shared__ float w1s[64*64];
  __shared__ float w2s[64*4];
  __shared__ float b1s[64], b2s[4];
  int t=threadIdx.x;
  for (int i=t;i<64*64;i+=256) w1s[i]=w1[i];
  for (int i=t;i<256;i+=256) w2s[i]=w2[i];
  if (t<64) b1s[t]=b1[t];
  if (t<4) b2s[t]=b2[t];
  __syncthreads();
  int n = blockIdx.x*256+t;
  if (n>=NN) return;
  float xr[64];
  #pragma unroll
  for (int k=0;k<16;k++){
    float4 v = ld4(h + (size_t)n*64 + k*4);
    xr[k*4+0]=v.x; xr[k*4+1]=v.y; xr[k*4+2]=v.z; xr[k*4+3]=v.w;
  }
  float a0=b2s[0],a1=b2s[1],a2=b2s[2],a3=b2s[3];
  for (int o=0;o<64;o++){
    float a=b1s[o];
    #pragma unroll
    for (int k=0;k<64;k++) a += xr[k]*w1s[k*64+o];
    a = fmaxf(a,0.f);
    a0 += a*w2s[o*4+0]; a1 += a*w2s[o*4+1]; a2 += a*w2s[o*4+2]; a3 += a*w2s[o*4+3];
  }
  out[(size_t)n*4+0]=a0; out[(size_t)n*4+1]=a1; out[(size_t)n*4+2]=a2; out[(size_t)n*4+3]=a3;
}

extern "C" void kernel_launch(void* const* d_in, const int* in_sizes, int n_in,
                              void* d_out, int out_size, void* d_ws, size_t ws_size,
                              hipStream_t stream){
  const float* x   = (const float*)d_in[0];
  const float* xm  = (const float*)d_in[1];
  const int*   ei  = (const int*)d_in[2];
  const float* ea  = (const float*)d_in[3];
  const int* batch = (const int*)d_in[5];
  const float* enc_w1=(const float*)d_in[6],  *enc_b1=(const float*)d_in[7];
  const float* enc_w2=(const float*)d_in[8],  *enc_b2=(const float*)d_in[9];
  const float* msg_w1=(const float*)d_in[10], *msg_b1=(const float*)d_in[11];
  const float* msg_w2=(const float*)d_in[12], *msg_b2=(const float*)d_in[13];
  const float* upd_w1=(const float*)d_in[14], *upd_b1=(const float*)d_in[15];
  const float* upd_w2=(const float*)d_in[16], *upd_b2=(const float*)d_in[17];
  const float* dec_w1=(const float*)d_in[18], *dec_b1=(const float*)d_in[19];
  const float* dec_w2=(const float*)d_in[20], *dec_b2=(const float*)d_in[21];
  const int* srcp = ei;
  const int* dstp = ei + EE;

  char* ws = (char*)d_ws;
  // layout: zero region [agg|cnt|xg_sum|xbc_sum|ncnt|bccnt] is contiguous -> single zero kernel
  float* h32     = (float*)(ws + 0);             // 12,800,000
  int*   agg     = (int*)  (ws + 12800000);      // 12,800,000
  int*   cnt     = (int*)  (ws + 25600000);      //    200,000
  unsigned long long* xg_sum  = (unsigned long long*)(ws + 25800000);  // 4096
  unsigned long long* xbc_sum = (unsigned long long*)(ws + 25804096);  // 4096
  float* ncnt    = (float*)(ws + 25808192);      //        32
  float* bccnt   = (float*)(ws + 25808224);      //        32
  short* h16     = (short*)(ws + 25808256);      //  6,400,000
  float* inv     = (float*)(ws + 32208256);      //    200,000
  short* xg16    = (short*)(ws + 32408256);      //      1024
  short* xbc16   = (short*)(ws + 32409280);      //      1024
  short* mw1p    = (short*)(ws + 32410304);      //     18432
  short* mw2p    = (short*)(ws + 32428736);      //      8192
  short* uw1p    = (short*)(ws + 32436928);      //     32768
  short* uw2p    = (short*)(ws + 32469696);      //      8192
  int*   offs    = (int*)  (ws + 32477888);      //    200,000
  int*   srcs_s  = (int*)  (ws + 32677888);      //  2,000,896
  int*   dsts_s  = (int*)  (ws + 34678784);      //  2,000,896
  short* ea16s   = (short*)(ws + 36679680);      //  4,001,792
  int*   bsum    = (int*)  (ws + 40681472);      //       800
  int*   boff    = (int*)  (ws + 40682272);      //       800
  int*   perm    = (int*)  (ws + 40683072);      //  2,000,896
  const size_t WS_NEED_SORT = 42683968;
  const int useSort = (ws_size >= WS_NEED_SORT) ? 1 : 0;

  // single fast zero pass: agg + cnt + xg_sum + xbc_sum + ncnt + bccnt (13,008,256 B = 813,016 int4)
  k_zero<<<2048, 256, 0, stream>>>((int4*)(ws + 12800000), 813016);
  k_wpack<<<34, 256, 0, stream>>>(msg_w1, msg_w2, upd_w1, upd_w2, mw1p, mw2p, uw1p, uw2p);
  k_count<<<(EE+255)/256, 256, 0, stream>>>(dstp, cnt);
  if (useSort){
    k_scanA<<<NB, 256, 0, stream>>>(cnt, bsum);
    k_scanB<<<1, 256, 0, stream>>>(bsum, boff);
    k_scanC_prep<<<NB, 256, 0, stream>>>(cnt, boff, offs, inv, batch, xm, ncnt, bccnt);
    k_scat1<<<(EE+255)/256, 256, 0, stream>>>(dstp, offs, perm);
    k_scat2<<<(EE+255)/256, 256, 0, stream>>>(perm, srcp, dstp, ea, srcs_s, dsts_s, ea16s);
  } else {
    k_prep<<<(NN+255)/256, 256, 0, stream>>>(cnt, inv, batch, xm, ncnt, bccnt);
  }
  k_enc<<<(NN+255)/256, 256, 0, stream>>>(x, xm, enc_w1, enc_b1, enc_w2, enc_b2, h32, h16);
  k_gred<<<512, 256, 0, stream>>>(h32, batch, xm, xg_sum, xbc_sum, 1);

  if (useSort){
    for (int rp=0; rp<4; rp++){
      // msg block 0 performs gfin (xg_sum from gred at rp=0, from upd(rp-1) after)
      k_msg_s<<<(EE+63)/64, 64, 0, stream>>>(h16, srcs_s, dsts_s, ea16s, mw1p, msg_b1, mw2p, msg_b2, agg,
                                             xg_sum, xbc_sum, ncnt, bccnt, xg16, xbc16, (rp==0)?1:0);
      int withG = (rp < 3) ? 1 : 0;
      k_upd<<<(NN+31)/32, 64, 0, stream>>>(h32, h16, agg, inv, batch, xg16, xbc16, uw1p, upd_b1, uw2p, upd_b2, xg_sum, withG);
    }
  } else {
    k_gfin<<<1, 512, 0, stream>>>(xg_sum, xbc_sum, ncnt, bccnt, xg16, xbc16, 1);
    for (int rp=0; rp<4; rp++){
      k_msg_atomic<<<(EE+255)/256, 256, 0, stream>>>(h16, srcp, dstp, ea, mw1p, msg_b1, mw2p, msg_b2, agg);
      int withG = (rp < 3) ? 1 : 0;
      k_upd<<<(NN+31)/32, 64, 0, stream>>>(h32, h16, agg, inv, batch, xg16, xbc16, uw1p, upd_b1, uw2p, upd_b2, xg_sum, withG);
      if (withG) k_gfin<<<1, 512, 0, stream>>>(xg_sum, xbc_sum, ncnt, bccnt, xg16, xbc16, 0);
    }
  }
  k_dec<<<(NN+255)/256, 256, 0, stream>>>(h32, dec_w1, dec_b1, dec_w2, dec_b2, (float*)d_out);
}